// Round 6
// baseline (793.841 us; speedup 1.0000x reference)
//
#include <hip/hip_runtime.h>
#include <hip/hip_bf16.h>

#define N_NODES 100000
#define N_EDGES 1600000

#define NBKT 782                 // ceil(N_NODES / 128)

#define WPREP_BLOCKS 384
#define HIST_BLOCKS 240
#define HIST_CHUNK 6667          // ceil(N_EDGES / 240)
#define XBF_BLOCKS 6250          // N_NODES*16/256

#define SCATB 480
#define SCHUNK 3334              // 480*3334 >= N_EDGES

#define SORT_BLOCKS 40
#define SORT_CHUNK 2500          // 40 * 2500 = 100000

#define NSTRIPS 6250             // N_NODES / 16 (exact)
#define GEMM_BLOCKS 782          // ceil(NSTRIPS / 8 waves)

typedef __attribute__((ext_vector_type(8))) short short8v;
typedef __attribute__((ext_vector_type(4))) float float4v;

__device__ __forceinline__ unsigned short f2bf(float f) {
    unsigned int u = __float_as_uint(f);
    u = (u + 0x7FFFu + ((u >> 16) & 1u)) >> 16;   // RTNE
    return (unsigned short)u;
}
__device__ __forceinline__ float bf2f(unsigned short b) {
    return __uint_as_float((unsigned int)b << 16);
}

// async global->LDS, 16B per lane. LDS dest must be linear (wave base + lane*16);
// swizzle goes on the GLOBAL source address (rule #21: both-sides-or-neither).
typedef __attribute__((address_space(1))) const unsigned int gld_g_t;
typedef __attribute__((address_space(3))) unsigned int gld_l_t;
__device__ __forceinline__ void gld_lds16(const void* g, void* l) {
    __builtin_amdgcn_global_load_lds((gld_g_t*)g, (gld_l_t*)l, 16, 0, 0);
}

// swizzled ds_read index (shorts): XOR byte ^= ((row&7)<<4) within a row
#define SWZ128(row, ksh) ((row) * 128 + ((ksh) ^ (((row) & 7) << 3)))   // 128-short rows
#define SWZ256(row, ksh) ((row) * 256 + ((ksh) ^ (((row) & 7) << 3)))   // 256-short rows

// ---------------- mega front-end: wprep (0..383) | edge histogram (384..623) | x->bf16 (624..) ----------------
__global__ __launch_bounds__(256) void mega0_kernel(const float* __restrict__ Wr1, const float* __restrict__ Wl1,
                                                    const float* __restrict__ Wres,
                                                    const float* __restrict__ Wl2, const float* __restrict__ Wr2,
                                                    const float* __restrict__ Wl3, const float* __restrict__ Wr3,
                                                    unsigned short* __restrict__ Bt1,
                                                    unsigned short* __restrict__ Bt2,
                                                    unsigned short* __restrict__ Bt3,
                                                    const int* __restrict__ ei, int* __restrict__ csr_hist,
                                                    const float* __restrict__ x, unsigned short* __restrict__ xsrc) {
    __shared__ int h[NBKT];
    int tid = threadIdx.x;
    int bid = blockIdx.x;
    if (bid < WPREP_BLOCKS) {
        int idx = bid * 256 + tid;
        int seg = idx >> 15;          // 32768 elements per segment
        int loc = idx & 32767;
        if (seg == 0) {
            int n = loc >> 7;
            int k = loc & 127;
            float v;
            if (n < 128) v = (k < 64) ? Wr1[k * 128 + n] : Wl1[(k - 64) * 128 + n];
            else         v = (k < 64) ? Wres[k * 128 + (n - 128)] : 0.f;
            Bt1[loc] = f2bf(v);
        } else if (seg == 1) {
            int n = loc >> 8;
            int k = loc & 255;
            float v = (k < 128) ? Wr2[k * 128 + n] : Wl2[(k - 128) * 128 + n];
            Bt2[loc] = f2bf(v);
        } else {
            int n = loc >> 8;
            int k = loc & 255;
            float v = (k < 128) ? Wr3[k * 128 + n] : Wl3[(k - 128) * 128 + n];
            Bt3[loc] = f2bf(v);
        }
    } else if (bid < WPREP_BLOCKS + HIST_BLOCKS) {
        for (int i = tid; i < NBKT; i += 256) h[i] = 0;
        __syncthreads();
        int start = (bid - WPREP_BLOCKS) * HIST_CHUNK;
        int end = start + HIST_CHUNK; if (end > N_EDGES) end = N_EDGES;
        for (int i = start + tid; i < end; i += 256) {
            int d = ei[N_EDGES + i];
            atomicAdd(&h[d >> 7], 1);
        }
        __syncthreads();
        for (int i = tid; i < NBKT; i += 256)
            if (h[i]) atomicAdd(&csr_hist[i], h[i]);
    } else {
        int idx = (bid - WPREP_BLOCKS - HIST_BLOCKS) * 256 + tid;   // one float4 per thread
        if (idx < N_NODES * 16) {
            int node = idx >> 4;
            int f0 = (idx & 15) * 4;
            float4 v = *(const float4*)(x + (size_t)idx * 4);
            ushort4 o;
            o.x = f2bf(v.x); o.y = f2bf(v.y); o.z = f2bf(v.z); o.w = f2bf(v.w);
            *(ushort4*)(xsrc + (size_t)node * 64 + f0) = o;
        }
    }
}

// ---------------- single-block exclusive scan of the 782-bin histogram ----------------
__global__ __launch_bounds__(1024) void scan782_kernel(const int* __restrict__ hist, int* __restrict__ base) {
    __shared__ int lds[1024];
    int tid = threadIdx.x;
    int v = (tid < NBKT) ? hist[tid] : 0;
    lds[tid] = v;
    __syncthreads();
    for (int off = 1; off < 1024; off <<= 1) {
        int y = 0;
        if (tid >= off) y = lds[tid - off];
        __syncthreads();
        if (tid >= off) lds[tid] += y;
        __syncthreads();
    }
    if (tid < NBKT) base[tid] = lds[tid] - v;     // exclusive
    if (tid == 0) base[NBKT] = N_EDGES;
}

// ---------------- scatter edges into bucket-grouped packed[] (global atomic positions) ----------------
__global__ __launch_bounds__(256) void bscat_kernel(const int* __restrict__ ei, const int* __restrict__ base,
                                                    int* __restrict__ cnt, int* __restrict__ packed) {
    int tid = threadIdx.x;
    int start = blockIdx.x * SCHUNK;
    int end = start + SCHUNK; if (end > N_EDGES) end = N_EDGES;
    for (int i = start + tid; i < end; i += 256) {
        int s = ei[i];
        int d = ei[N_EDGES + i];
        int b = d >> 7;
        int pos = base[b] + atomicAdd(&cnt[b], 1);
        packed[pos] = (s << 7) | (d & 127);
    }
}

// merged: per-bucket degree count + LDS scan -> deg[], row_ptr[]; dsort chunk-hist; then fill col.
__global__ __launch_bounds__(256) void bkt_build_kernel(const int* __restrict__ packed, const int* __restrict__ base,
                                                        int* __restrict__ deg, int* __restrict__ row_ptr,
                                                        int* __restrict__ col, int* __restrict__ dbh) {
    __shared__ int c[128];
    __shared__ int rp[128];
    int tid = threadIdx.x;
    int s0 = base[blockIdx.x];
    int s1 = base[blockIdx.x + 1];
    if (tid < 128) c[tid] = 0;
    __syncthreads();
    for (int i = s0 + tid; i < s1; i += 256) atomicAdd(&c[packed[i] & 127], 1);
    __syncthreads();
    if (tid < 128) rp[tid] = c[tid];
    __syncthreads();
    for (int off = 1; off < 128; off <<= 1) {
        int y = 0;
        if (tid >= off && tid < 128) y = rp[tid - off];
        __syncthreads();
        if (tid >= off && tid < 128) rp[tid] += y;
        __syncthreads();
    }
    int node = blockIdx.x * 128 + tid;
    if (tid < 128) {
        rp[tid] = s0 + rp[tid] - c[tid];   // exclusive in-bucket prefix + bucket base
        if (node < N_NODES) {
            deg[node] = c[tid];
            row_ptr[node] = rp[tid];
            int b = 63 - min(c[tid], 63);              // descending-degree bin
            atomicAdd(&dbh[b * SORT_BLOCKS + node / SORT_CHUNK], 1);
        }
        c[tid] = 0;
    }
    if (blockIdx.x == 0 && tid == 0) row_ptr[N_NODES] = N_EDGES;
    __syncthreads();
    for (int i = s0 + tid; i < s1; i += 256) {
        int p = packed[i];
        int dl = p & 127;
        int pos = rp[dl] + atomicAdd(&c[dl], 1);
        col[pos] = p >> 7;
    }
}

// scatter; each block self-scans the full dbh[2560] in LDS (exclusive prefix); DESCENDING degree
__global__ __launch_bounds__(256) void dsort_scat_kernel(const int* __restrict__ deg, const int* __restrict__ bh,
                                                         int* __restrict__ ord) {
    __shared__ int sbh[64 * SORT_BLOCKS];
    __shared__ int ps[256];
    __shared__ int h[64];
    int tid = threadIdx.x;
    int v[10];
    int s = 0;
    #pragma unroll
    for (int k = 0; k < 10; k++) { v[k] = bh[tid * 10 + k]; s += v[k]; }
    ps[tid] = s;
    if (tid < 64) h[tid] = 0;
    __syncthreads();
    for (int off = 1; off < 256; off <<= 1) {
        int y = 0;
        if (tid >= off) y = ps[tid - off];
        __syncthreads();
        if (tid >= off) ps[tid] += y;
        __syncthreads();
    }
    int run = ps[tid] - s;
    #pragma unroll
    for (int k = 0; k < 10; k++) { sbh[tid * 10 + k] = run; run += v[k]; }
    __syncthreads();
    int start = blockIdx.x * SORT_CHUNK;
    int end = start + SORT_CHUNK; if (end > N_NODES) end = N_NODES;
    for (int i = start + tid; i < end; i += 256) {
        int b = 63 - min(deg[i], 63);
        int pos = sbh[b * SORT_BLOCKS + blockIdx.x] + atomicAdd(&h[b], 1);
        ord[pos] = i;
    }
}

#define ACC4(u) { a0 += bf2f(u.x); a1 += bf2f(u.y); a2 += bf2f(u.z); a3 += bf2f(u.w); }

// ---------------- layer-1 agg: mean of xsrc[j,:] -> aggx[i,:]; 16 lanes/node ----------------
__global__ __launch_bounds__(256) void agg64_kernel(const unsigned short* __restrict__ xsrc,
                                                    unsigned short* __restrict__ aggx,
                                                    const int* __restrict__ row_ptr, const int* __restrict__ col,
                                                    const int* __restrict__ ord) {
    int tid = threadIdx.x;
    int slot = blockIdx.x * 16 + (tid >> 4);
    if (slot >= N_NODES) return;
    int i = ord[slot];
    int f0 = (tid & 15) * 4;
    int s = row_ptr[i], e = row_ptr[i + 1];
    float a0 = 0.f, a1 = 0.f, a2 = 0.f, a3 = 0.f;
    int t = s;
    while (t + 7 < e) {
        int j0 = col[t], j1 = col[t + 1], j2 = col[t + 2], j3 = col[t + 3];
        int j4 = col[t + 4], j5 = col[t + 5], j6 = col[t + 6], j7 = col[t + 7];
        ushort4 u0 = *(const ushort4*)(xsrc + (size_t)j0 * 64 + f0);
        ushort4 u1 = *(const ushort4*)(xsrc + (size_t)j1 * 64 + f0);
        ushort4 u2 = *(const ushort4*)(xsrc + (size_t)j2 * 64 + f0);
        ushort4 u3 = *(const ushort4*)(xsrc + (size_t)j3 * 64 + f0);
        ushort4 u4 = *(const ushort4*)(xsrc + (size_t)j4 * 64 + f0);
        ushort4 u5 = *(const ushort4*)(xsrc + (size_t)j5 * 64 + f0);
        ushort4 u6 = *(const ushort4*)(xsrc + (size_t)j6 * 64 + f0);
        ushort4 u7 = *(const ushort4*)(xsrc + (size_t)j7 * 64 + f0);
        ACC4(u0) ACC4(u1) ACC4(u2) ACC4(u3) ACC4(u4) ACC4(u5) ACC4(u6) ACC4(u7)
        t += 8;
    }
    if (t + 3 < e) {
        int j0 = col[t], j1 = col[t + 1], j2 = col[t + 2], j3 = col[t + 3];
        ushort4 u0 = *(const ushort4*)(xsrc + (size_t)j0 * 64 + f0);
        ushort4 u1 = *(const ushort4*)(xsrc + (size_t)j1 * 64 + f0);
        ushort4 u2 = *(const ushort4*)(xsrc + (size_t)j2 * 64 + f0);
        ushort4 u3 = *(const ushort4*)(xsrc + (size_t)j3 * 64 + f0);
        ACC4(u0) ACC4(u1) ACC4(u2) ACC4(u3)
        t += 4;
    }
    if (t + 1 < e) {
        int j0 = col[t], j1 = col[t + 1];
        ushort4 u0 = *(const ushort4*)(xsrc + (size_t)j0 * 64 + f0);
        ushort4 u1 = *(const ushort4*)(xsrc + (size_t)j1 * 64 + f0);
        ACC4(u0) ACC4(u1)
        t += 2;
    }
    if (t < e) {
        ushort4 u0 = *(const ushort4*)(xsrc + (size_t)col[t] * 64 + f0);
        ACC4(u0)
    }
    float di = 1.0f / fmaxf((float)(e - s), 1.0f);
    ushort4 o;
    o.x = f2bf(a0 * di); o.y = f2bf(a1 * di); o.z = f2bf(a2 * di); o.w = f2bf(a3 * di);
    *(ushort4*)(aggx + (size_t)i * 64 + f0) = o;
}

// ---------------- layers 2/3 agg: mean of hsrc[j,:] -> aggh[i,:]; 32 lanes/node ----------------
__global__ __launch_bounds__(256) void agg128_kernel(const unsigned short* __restrict__ hsrc,
                                                     unsigned short* __restrict__ aggh,
                                                     const int* __restrict__ row_ptr, const int* __restrict__ col,
                                                     const int* __restrict__ ord) {
    int tid = threadIdx.x;
    int slot = blockIdx.x * 8 + (tid >> 5);
    if (slot >= N_NODES) return;
    int i = ord[slot];
    int f0 = (tid & 31) * 4;
    int s = row_ptr[i], e = row_ptr[i + 1];
    float a0 = 0.f, a1 = 0.f, a2 = 0.f, a3 = 0.f;
    int t = s;
    while (t + 7 < e) {
        int j0 = col[t], j1 = col[t + 1], j2 = col[t + 2], j3 = col[t + 3];
        int j4 = col[t + 4], j5 = col[t + 5], j6 = col[t + 6], j7 = col[t + 7];
        ushort4 u0 = *(const ushort4*)(hsrc + (size_t)j0 * 128 + f0);
        ushort4 u1 = *(const ushort4*)(hsrc + (size_t)j1 * 128 + f0);
        ushort4 u2 = *(const ushort4*)(hsrc + (size_t)j2 * 128 + f0);
        ushort4 u3 = *(const ushort4*)(hsrc + (size_t)j3 * 128 + f0);
        ushort4 u4 = *(const ushort4*)(hsrc + (size_t)j4 * 128 + f0);
        ushort4 u5 = *(const ushort4*)(hsrc + (size_t)j5 * 128 + f0);
        ushort4 u6 = *(const ushort4*)(hsrc + (size_t)j6 * 128 + f0);
        ushort4 u7 = *(const ushort4*)(hsrc + (size_t)j7 * 128 + f0);
        ACC4(u0) ACC4(u1) ACC4(u2) ACC4(u3) ACC4(u4) ACC4(u5) ACC4(u6) ACC4(u7)
        t += 8;
    }
    if (t + 3 < e) {
        int j0 = col[t], j1 = col[t + 1], j2 = col[t + 2], j3 = col[t + 3];
        ushort4 u0 = *(const ushort4*)(hsrc + (size_t)j0 * 128 + f0);
        ushort4 u1 = *(const ushort4*)(hsrc + (size_t)j1 * 128 + f0);
        ushort4 u2 = *(const ushort4*)(hsrc + (size_t)j2 * 128 + f0);
        ushort4 u3 = *(const ushort4*)(hsrc + (size_t)j3 * 128 + f0);
        ACC4(u0) ACC4(u1) ACC4(u2) ACC4(u3)
        t += 4;
    }
    if (t + 1 < e) {
        int j0 = col[t], j1 = col[t + 1];
        ushort4 u0 = *(const ushort4*)(hsrc + (size_t)j0 * 128 + f0);
        ushort4 u1 = *(const ushort4*)(hsrc + (size_t)j1 * 128 + f0);
        ACC4(u0) ACC4(u1)
        t += 2;
    }
    if (t < e) {
        ushort4 u0 = *(const ushort4*)(hsrc + (size_t)col[t] * 128 + f0);
        ACC4(u0)
    }
    float di = 1.0f / fmaxf((float)(e - s), 1.0f);
    ushort4 o;
    o.x = f2bf(a0 * di); o.y = f2bf(a1 * di); o.z = f2bf(a2 * di); o.w = f2bf(a3 * di);
    *(ushort4*)(aggh + (size_t)i * 128 + f0) = o;
}

// ---------------- layer-1 fused GEMM+LN (weight-stationary, A streamed from global) ----------------
__global__ __launch_bounds__(512) void mgemm1_ln_kernel(const unsigned short* __restrict__ Ax,
                                                        const unsigned short* __restrict__ Aa,
                                                        const unsigned short* __restrict__ Bt,
                                                        const float* __restrict__ b1, const float* __restrict__ ln_g,
                                                        const float* __restrict__ ln_b, const float* __restrict__ bres,
                                                        unsigned short* __restrict__ hsrc) {
    __shared__ unsigned short Bs[32768];   // 256 n-rows x 128 k (rows 0..127 = T, 128..255 = Wres)
    int tid = threadIdx.x;
    int wave = tid >> 6, lane = tid & 63;
    int lm = lane & 15, lk = (lane >> 4) * 8;

    #pragma unroll
    for (int rnd = 0; rnd < 8; rnd++) {
        int Lb = rnd * 8192 + tid * 16;           // linear LDS byte offset (uniform + lane*16)
        int row = Lb >> 8;                        // 256B rows
        int sb = (Lb & 255) ^ ((row & 7) << 4);   // pre-swizzled source byte-in-row
        gld_lds16(Bt + (size_t)row * 128 + (sb >> 1), &Bs[Lb >> 1]);
    }
    __syncthreads();

    int strip = blockIdx.x * 8 + wave;
    if (strip >= NSTRIPS) return;
    int m0 = strip * 16;

    float4v accT[8], accR[8];
    #pragma unroll
    for (int j = 0; j < 8; j++) { accT[j] = (float4v)0.f; accR[j] = (float4v)0.f; }

    const unsigned short* arx = Ax + (size_t)(m0 + lm) * 64 + lk;
    const unsigned short* ara = Aa + (size_t)(m0 + lm) * 64 + lk;
    #pragma unroll
    for (int k0 = 0; k0 < 128; k0 += 32) {
        short8v af = (k0 < 64) ? *(const short8v*)(arx + k0) : *(const short8v*)(ara + (k0 - 64));
        short8v bf[8];
        #pragma unroll
        for (int j = 0; j < 8; j++)
            bf[j] = *(const short8v*)&Bs[SWZ128(j * 16 + lm, k0 + lk)];
        #pragma unroll
        for (int j = 0; j < 8; j++)
            accT[j] = __builtin_amdgcn_mfma_f32_16x16x32_bf16(af, bf[j], accT[j], 0, 0, 0);
        if (k0 < 64) {                            // residual path only has k<64 support
            short8v bg[8];
            #pragma unroll
            for (int j = 0; j < 8; j++)
                bg[j] = *(const short8v*)&Bs[SWZ128(128 + j * 16 + lm, k0 + lk)];
            #pragma unroll
            for (int j = 0; j < 8; j++)
                accR[j] = __builtin_amdgcn_mfma_f32_16x16x32_bf16(af, bg[j], accR[j], 0, 0, 0);
        }
    }

    float b1v[8], gv[8], bbv[8], brv[8];
    #pragma unroll
    for (int j = 0; j < 8; j++) {
        int cc = j * 16 + lm;
        b1v[j] = b1[cc]; gv[j] = ln_g[cc]; bbv[j] = ln_b[cc]; brv[j] = bres[cc];
    }
    int q4 = lane >> 4;
    #pragma unroll
    for (int r = 0; r < 4; r++) {
        float sp = 0.f, sq = 0.f;
        #pragma unroll
        for (int j = 0; j < 8; j++) {
            float tv = accT[j][r] + b1v[j];
            sp += tv; sq += tv * tv;
        }
        #pragma unroll
        for (int off = 1; off < 16; off <<= 1) {
            sp += __shfl_xor(sp, off);
            sq += __shfl_xor(sq, off);
        }
        float mu = sp * (1.f / 128.f);
        float var = sq * (1.f / 128.f) - mu * mu;
        float rstd = rsqrtf(var + 1e-5f);
        int gm = m0 + q4 * 4 + r;
        #pragma unroll
        for (int j = 0; j < 8; j++) {
            float tv = accT[j][r] + b1v[j];
            float y = fmaxf((tv - mu) * rstd * gv[j] + bbv[j], 0.f) + accR[j][r] + brv[j];
            hsrc[(size_t)gm * 128 + j * 16 + lm] = f2bf(y);
        }
    }
}

// ---------------- layer-2 GEMM: hsrc = relu([hsrc|aggh] @ Bt2^T + b2), in-place safe ----------------
__global__ __launch_bounds__(512) void mgemm_kernel(const unsigned short* __restrict__ Ah,
                                                    const unsigned short* __restrict__ Aa,
                                                    const unsigned short* __restrict__ Bt,
                                                    const float* __restrict__ bias,
                                                    unsigned short* __restrict__ C) {
    __shared__ unsigned short Bs[32768];   // 128 n-rows x 256 k
    int tid = threadIdx.x;
    int wave = tid >> 6, lane = tid & 63;
    int lm = lane & 15, lk = (lane >> 4) * 8;

    #pragma unroll
    for (int rnd = 0; rnd < 8; rnd++) {
        int Lb = rnd * 8192 + tid * 16;
        int row = Lb >> 9;                        // 512B rows
        int sb = (Lb & 511) ^ ((row & 7) << 4);
        gld_lds16(Bt + ((size_t)row << 8) + (sb >> 1), &Bs[Lb >> 1]);
    }
    __syncthreads();

    int strip = blockIdx.x * 8 + wave;
    if (strip >= NSTRIPS) return;
    int m0 = strip * 16;

    float4v acc[8];
    #pragma unroll
    for (int j = 0; j < 8; j++) acc[j] = (float4v)0.f;

    const unsigned short* arh = Ah + (size_t)(m0 + lm) * 128 + lk;
    const unsigned short* ara = Aa + (size_t)(m0 + lm) * 128 + lk;
    #pragma unroll
    for (int k0 = 0; k0 < 256; k0 += 32) {
        short8v af = (k0 < 128) ? *(const short8v*)(arh + k0) : *(const short8v*)(ara + (k0 - 128));
        short8v bf[8];
        #pragma unroll
        for (int j = 0; j < 8; j++)
            bf[j] = *(const short8v*)&Bs[SWZ256(j * 16 + lm, k0 + lk)];
        #pragma unroll
        for (int j = 0; j < 8; j++)
            acc[j] = __builtin_amdgcn_mfma_f32_16x16x32_bf16(af, bf[j], acc[j], 0, 0, 0);
    }

    int q4 = lane >> 4;
    #pragma unroll
    for (int j = 0; j < 8; j++) {
        int cc = j * 16 + lm;
        float bv = bias[cc];
        #pragma unroll
        for (int r = 0; r < 4; r++) {
            int m = m0 + q4 * 4 + r;
            C[(size_t)m * 128 + cc] = f2bf(fmaxf(acc[j][r] + bv, 0.f));
        }
    }
}

// ---------------- layer-3 fused GEMM+pq (h3 never stored) ----------------
__global__ __launch_bounds__(512) void mgemm_pq_kernel(const unsigned short* __restrict__ Ah,
                                                       const unsigned short* __restrict__ Aa,
                                                       const unsigned short* __restrict__ Bt,
                                                       const float* __restrict__ bias,
                                                       const float* __restrict__ Wl4, const float* __restrict__ Wr4,
                                                       const float* __restrict__ b4,
                                                       float* __restrict__ p, float* __restrict__ q) {
    __shared__ unsigned short Bs[32768];   // 128 n-rows x 256 k
    int tid = threadIdx.x;
    int wave = tid >> 6, lane = tid & 63;
    int lm = lane & 15, lk = (lane >> 4) * 8;

    #pragma unroll
    for (int rnd = 0; rnd < 8; rnd++) {
        int Lb = rnd * 8192 + tid * 16;
        int row = Lb >> 9;
        int sb = (Lb & 511) ^ ((row & 7) << 4);
        gld_lds16(Bt + ((size_t)row << 8) + (sb >> 1), &Bs[Lb >> 1]);
    }
    __syncthreads();

    int strip = blockIdx.x * 8 + wave;
    if (strip >= NSTRIPS) return;
    int m0 = strip * 16;

    float4v acc[8];
    #pragma unroll
    for (int j = 0; j < 8; j++) acc[j] = (float4v)0.f;

    const unsigned short* arh = Ah + (size_t)(m0 + lm) * 128 + lk;
    const unsigned short* ara = Aa + (size_t)(m0 + lm) * 128 + lk;
    #pragma unroll
    for (int k0 = 0; k0 < 256; k0 += 32) {
        short8v af = (k0 < 128) ? *(const short8v*)(arh + k0) : *(const short8v*)(ara + (k0 - 128));
        short8v bf[8];
        #pragma unroll
        for (int j = 0; j < 8; j++)
            bf[j] = *(const short8v*)&Bs[SWZ256(j * 16 + lm, k0 + lk)];
        #pragma unroll
        for (int j = 0; j < 8; j++)
            acc[j] = __builtin_amdgcn_mfma_f32_16x16x32_bf16(af, bf[j], acc[j], 0, 0, 0);
    }

    float b3v[8], wlv[8], wrv[8];
    #pragma unroll
    for (int j = 0; j < 8; j++) {
        int cc = j * 16 + lm;
        b3v[j] = bias[cc]; wlv[j] = Wl4[cc]; wrv[j] = Wr4[cc];
    }
    float b4v = b4[0];
    int q4 = lane >> 4;
    #pragma unroll
    for (int r = 0; r < 4; r++) {
        float pp = 0.f, qq = 0.f;
        #pragma unroll
        for (int j = 0; j < 8; j++) {
            float hv = fmaxf(acc[j][r] + b3v[j], 0.f);
            pp += hv * wlv[j]; qq += hv * wrv[j];
        }
        #pragma unroll
        for (int off = 1; off < 16; off <<= 1) {
            pp += __shfl_xor(pp, off);
            qq += __shfl_xor(qq, off);
        }
        if (lm == 0) {
            int m = m0 + q4 * 4 + r;
            p[m] = pp;
            q[m] = qq + b4v;
        }
    }
}

__global__ __launch_bounds__(256) void final_kernel(const float* __restrict__ p, const float* __restrict__ q,
                                                    const int* __restrict__ row_ptr, const int* __restrict__ col,
                                                    float* __restrict__ out) {
    int i = blockIdx.x * 256 + threadIdx.x;   // original node id
    if (i >= N_NODES) return;
    int s = row_ptr[i], e = row_ptr[i + 1];
    float acc = 0.f;
    int t = s;
    for (; t + 7 < e; t += 8)
        acc += p[col[t]] + p[col[t + 1]] + p[col[t + 2]] + p[col[t + 3]]
             + p[col[t + 4]] + p[col[t + 5]] + p[col[t + 6]] + p[col[t + 7]];
    for (; t < e; t++) acc += p[col[t]];
    float di = 1.0f / fmaxf((float)(e - s), 1.0f);
    out[i] = acc * di + q[i];
}

// ---------------- launch ----------------

extern "C" void kernel_launch(void* const* d_in, const int* in_sizes, int n_in,
                              void* d_out, int out_size, void* d_ws, size_t ws_size,
                              hipStream_t stream) {
    const float* x    = (const float*)d_in[0];
    const int*   ei   = (const int*)d_in[1];
    const float* Wl1  = (const float*)d_in[2];
    const float* Wr1  = (const float*)d_in[3];
    const float* b1   = (const float*)d_in[4];
    const float* ln_g = (const float*)d_in[5];
    const float* ln_b = (const float*)d_in[6];
    const float* Wres = (const float*)d_in[7];
    const float* bres = (const float*)d_in[8];
    const float* Wl2  = (const float*)d_in[9];
    const float* Wr2  = (const float*)d_in[10];
    const float* b2   = (const float*)d_in[11];
    const float* Wl3  = (const float*)d_in[12];
    const float* Wr3  = (const float*)d_in[13];
    const float* b3   = (const float*)d_in[14];
    const float* Wl4  = (const float*)d_in[15];
    const float* Wr4  = (const float*)d_in[16];
    const float* b4   = (const float*)d_in[17];
    float* out = (float*)d_out;

    char* w = (char*)d_ws;
    size_t off = 0;
    auto alloc = [&](size_t bytes) -> void* {
        off = (off + 255) & ~(size_t)255;
        void* pp = w + off;
        off += bytes;
        return pp;
    };

    // meta block (single memset): csr_hist[782] | csr_cnt[782] | dbh[2560]
    int* meta     = (int*)alloc((NBKT + NBKT + 64 * SORT_BLOCKS) * 4);
    int* csr_hist = meta;
    int* csr_cnt  = meta + NBKT;
    int* dbh      = meta + 2 * NBKT;
    int* base     = (int*)alloc((NBKT + 1) * 4);
    int* deg      = (int*)alloc(N_NODES * 4);
    int* row_ptr  = (int*)alloc((N_NODES + 1) * 4);
    int* col      = (int*)alloc(N_EDGES * 4);
    int* ord      = (int*)alloc(N_NODES * 4);       // sorted slot -> original node (desc degree)
    unsigned short* Bt1  = (unsigned short*)alloc(256 * 128 * 2);
    unsigned short* Bt2  = (unsigned short*)alloc(128 * 256 * 2);
    unsigned short* Bt3  = (unsigned short*)alloc(128 * 256 * 2);
    unsigned short* xsrc = (unsigned short*)alloc((size_t)N_NODES * 64 * 2);   // x bf16 (compact)
    unsigned short* aggx = (unsigned short*)alloc((size_t)N_NODES * 64 * 2);   // agg(x)
    unsigned short* hsrc = (unsigned short*)alloc((size_t)N_NODES * 128 * 2);  // h bf16 (compact)
    unsigned short* aggh = (unsigned short*)alloc((size_t)N_NODES * 128 * 2);  // agg(h)
    int*   packed  = (int*)alloc((size_t)N_EDGES * 4);   // CSR build scratch
    float* p       = (float*)alloc(N_NODES * 4);
    float* q       = (float*)alloc(N_NODES * 4);
    (void)ws_size; (void)n_in; (void)in_sizes; (void)out_size;

    const int NB = (N_NODES + 255) / 256;

    // --- zero counters, then mega front-end: wprep | edge hist | x->bf16 ---
    hipMemsetAsync(meta, 0, (NBKT + NBKT + 64 * SORT_BLOCKS) * 4, stream);
    mega0_kernel<<<WPREP_BLOCKS + HIST_BLOCKS + XBF_BLOCKS, 256, 0, stream>>>(
        Wr1, Wl1, Wres, Wl2, Wr2, Wl3, Wr3, Bt1, Bt2, Bt3, ei, csr_hist, x, xsrc);

    // --- CSR build ---
    scan782_kernel<<<1, 1024, 0, stream>>>(csr_hist, base);
    bscat_kernel<<<SCATB, 256, 0, stream>>>(ei, base, csr_cnt, packed);
    bkt_build_kernel<<<NBKT, 256, 0, stream>>>(packed, base, deg, row_ptr, col, dbh);
    dsort_scat_kernel<<<SORT_BLOCKS, 256, 0, stream>>>(deg, dbh, ord);

    // --- layer 1: agg(x) -> aggx; fused GEMM+LN -> hsrc ---
    agg64_kernel<<<(N_NODES + 15) / 16, 256, 0, stream>>>(xsrc, aggx, row_ptr, col, ord);
    mgemm1_ln_kernel<<<GEMM_BLOCKS, 512, 0, stream>>>(xsrc, aggx, Bt1, b1, ln_g, ln_b, bres, hsrc);

    // --- layer 2: agg(h) -> aggh; GEMM [h|aggh] -> hsrc (bias+relu, in-place) ---
    agg128_kernel<<<(N_NODES + 7) / 8, 256, 0, stream>>>(hsrc, aggh, row_ptr, col, ord);
    mgemm_kernel<<<GEMM_BLOCKS, 512, 0, stream>>>(hsrc, aggh, Bt2, b2, hsrc);

    // --- layer 3: agg(h) -> aggh; fused GEMM+pq -> p, q (h3 never stored) ---
    agg128_kernel<<<(N_NODES + 7) / 8, 256, 0, stream>>>(hsrc, aggh, row_ptr, col, ord);
    mgemm_pq_kernel<<<GEMM_BLOCKS, 512, 0, stream>>>(hsrc, aggh, Bt3, b3, Wl4, Wr4, b4, p, q);

    // --- final ---
    final_kernel<<<NB, 256, 0, stream>>>(p, q, row_ptr, col, out);
}

// Round 7
// 437.831 us; speedup vs baseline: 1.8131x; 1.8131x over previous
//
#include <hip/hip_runtime.h>
#include <hip/hip_bf16.h>

#define N_NODES 100000
#define N_EDGES 1600000

#define NBKT 782                 // ceil(N_NODES / 128)
#define SCAT_BLOCKS 240
#define BKT_CHUNK 6667           // ceil(N_EDGES / 240)

#define WPREP_BLOCKS 384
#define XBF_BLOCKS 6250          // N_NODES*16/256

#define SORT_BLOCKS 40
#define SORT_CHUNK 2500          // 40 * 2500 = 100000
#define BH2_N (NBKT * SCAT_BLOCKS)   // 187680
#define BHB ((BH2_N + 1023) / 1024)  // 184

#define NSTRIPS 6250             // N_NODES / 16 (exact)
#define GEMM_BLOCKS 782          // ceil(NSTRIPS / 8 waves)

typedef __attribute__((ext_vector_type(8))) short short8v;
typedef __attribute__((ext_vector_type(4))) float float4v;

__device__ __forceinline__ unsigned short f2bf(float f) {
    unsigned int u = __float_as_uint(f);
    u = (u + 0x7FFFu + ((u >> 16) & 1u)) >> 16;   // RTNE
    return (unsigned short)u;
}
__device__ __forceinline__ float bf2f(unsigned short b) {
    return __uint_as_float((unsigned int)b << 16);
}

// async global->LDS, 16B per lane. LDS dest must be linear (wave base + lane*16);
// swizzle goes on the GLOBAL source address (rule #21: both-sides-or-neither).
typedef __attribute__((address_space(1))) const unsigned int gld_g_t;
typedef __attribute__((address_space(3))) unsigned int gld_l_t;
__device__ __forceinline__ void gld_lds16(const void* g, void* l) {
    __builtin_amdgcn_global_load_lds((gld_g_t*)g, (gld_l_t*)l, 16, 0, 0);
}

// swizzled ds_read index (shorts): XOR byte ^= ((row&7)<<4) within a row
#define SWZ128(row, ksh) ((row) * 128 + ((ksh) ^ (((row) & 7) << 3)))   // 128-short rows
#define SWZ256(row, ksh) ((row) * 256 + ((ksh) ^ (((row) & 7) << 3)))   // 256-short rows

// ---------------- mega front-end: wprep (0..383) | edge histogram -> bh2 (384..623) | x->bf16 (624..) ----------------
__global__ __launch_bounds__(256) void mega0_kernel(const float* __restrict__ Wr1, const float* __restrict__ Wl1,
                                                    const float* __restrict__ Wres,
                                                    const float* __restrict__ Wl2, const float* __restrict__ Wr2,
                                                    const float* __restrict__ Wl3, const float* __restrict__ Wr3,
                                                    unsigned short* __restrict__ Bt1,
                                                    unsigned short* __restrict__ Bt2,
                                                    unsigned short* __restrict__ Bt3,
                                                    const int* __restrict__ ei, int* __restrict__ bh2,
                                                    const float* __restrict__ x, unsigned short* __restrict__ xsrc) {
    __shared__ int h[NBKT];
    int tid = threadIdx.x;
    int bid = blockIdx.x;
    if (bid < WPREP_BLOCKS) {
        int idx = bid * 256 + tid;
        int seg = idx >> 15;          // 32768 elements per segment
        int loc = idx & 32767;
        if (seg == 0) {
            int n = loc >> 7;
            int k = loc & 127;
            float v;
            if (n < 128) v = (k < 64) ? Wr1[k * 128 + n] : Wl1[(k - 64) * 128 + n];
            else         v = (k < 64) ? Wres[k * 128 + (n - 128)] : 0.f;
            Bt1[loc] = f2bf(v);
        } else if (seg == 1) {
            int n = loc >> 8;
            int k = loc & 255;
            float v = (k < 128) ? Wr2[k * 128 + n] : Wl2[(k - 128) * 128 + n];
            Bt2[loc] = f2bf(v);
        } else {
            int n = loc >> 8;
            int k = loc & 255;
            float v = (k < 128) ? Wr3[k * 128 + n] : Wl3[(k - 128) * 128 + n];
            Bt3[loc] = f2bf(v);
        }
    } else if (bid < WPREP_BLOCKS + SCAT_BLOCKS) {
        int hb = bid - WPREP_BLOCKS;
        for (int i = tid; i < NBKT; i += 256) h[i] = 0;
        __syncthreads();
        int start = hb * BKT_CHUNK;
        int end = start + BKT_CHUNK; if (end > N_EDGES) end = N_EDGES;
        for (int i = start + tid; i < end; i += 256) {
            int d = ei[N_EDGES + i];
            atomicAdd(&h[d >> 7], 1);
        }
        __syncthreads();
        for (int i = tid; i < NBKT; i += 256) bh2[i * SCAT_BLOCKS + hb] = h[i];
    } else {
        int idx = (bid - WPREP_BLOCKS - SCAT_BLOCKS) * 256 + tid;   // one float4 per thread
        if (idx < N_NODES * 16) {
            int node = idx >> 4;
            int f0 = (idx & 15) * 4;
            float4 v = *(const float4*)(x + (size_t)idx * 4);
            ushort4 o;
            o.x = f2bf(v.x); o.y = f2bf(v.y); o.z = f2bf(v.z); o.w = f2bf(v.w);
            *(ushort4*)(xsrc + (size_t)node * 64 + f0) = o;
        }
    }
}

__global__ __launch_bounds__(256) void gscan_a_kernel(const int* __restrict__ in, int* __restrict__ bsum, int n) {
    __shared__ int lds[256];
    int tid = threadIdx.x;
    int base = blockIdx.x * 1024 + tid * 4;
    int s = 0;
    #pragma unroll
    for (int i = 0; i < 4; i++) s += (base + i < n) ? in[base + i] : 0;
    lds[tid] = s;
    __syncthreads();
    for (int off = 128; off; off >>= 1) {
        if (tid < off) lds[tid] += lds[tid + off];
        __syncthreads();
    }
    if (tid == 0) bsum[blockIdx.x] = lds[0];
}

// in-place exclusive scan apply; each block self-scans bsum (<=256 entries) in LDS
__global__ __launch_bounds__(256) void gscan_c_kernel(int* __restrict__ data, const int* __restrict__ bsum,
                                                      int nb, int n) {
    __shared__ int sb[256];
    __shared__ int lds[256];
    int tid = threadIdx.x;
    sb[tid] = (tid < nb) ? bsum[tid] : 0;
    __syncthreads();
    for (int off = 1; off < 256; off <<= 1) {
        int y = 0;
        if (tid >= off) y = sb[tid - off];
        __syncthreads();
        if (tid >= off) sb[tid] += y;
        __syncthreads();
    }
    int blockbase = (blockIdx.x == 0) ? 0 : sb[blockIdx.x - 1];

    int base = blockIdx.x * 1024 + tid * 4;
    int v[4];
    int s = 0;
    #pragma unroll
    for (int i = 0; i < 4; i++) {
        v[i] = (base + i < n) ? data[base + i] : 0;
        s += v[i];
    }
    lds[tid] = s;
    __syncthreads();
    for (int off = 1; off < 256; off <<= 1) {
        int y = 0;
        if (tid >= off) y = lds[tid - off];
        __syncthreads();
        if (tid >= off) lds[tid] += y;
        __syncthreads();
    }
    int run = blockbase + lds[tid] - s;
    #pragma unroll
    for (int i = 0; i < 4; i++) {
        if (base + i < n) data[base + i] = run;
        run += v[i];
    }
}

// scatter with LDS-privatized counters + precomputed per-(bucket,block) bases (bh2 scanned)
__global__ __launch_bounds__(256) void bkt_scatter2_kernel(const int* __restrict__ ei, const int* __restrict__ bh2,
                                                           int* __restrict__ packed) {
    __shared__ int h[NBKT];
    __shared__ int base[NBKT];
    int tid = threadIdx.x;
    for (int i = tid; i < NBKT; i += 256) { h[i] = 0; base[i] = bh2[i * SCAT_BLOCKS + blockIdx.x]; }
    __syncthreads();
    int start = blockIdx.x * BKT_CHUNK;
    int end = start + BKT_CHUNK; if (end > N_EDGES) end = N_EDGES;
    for (int i = start + tid; i < end; i += 256) {
        int s = ei[i];
        int d = ei[N_EDGES + i];
        int b = d >> 7;
        int pos = base[b] + atomicAdd(&h[b], 1);
        packed[pos] = (s << 7) | (d & 127);
    }
}

// merged: per-bucket degree count + LDS scan -> deg[], row_ptr[]; dsort chunk-hist; then fill col.
__global__ __launch_bounds__(256) void bkt_build_kernel(const int* __restrict__ packed, const int* __restrict__ bh2,
                                                        int* __restrict__ deg, int* __restrict__ row_ptr,
                                                        int* __restrict__ col, int* __restrict__ dbh) {
    __shared__ int c[128];
    __shared__ int rp[128];
    int tid = threadIdx.x;
    int s0 = bh2[blockIdx.x * SCAT_BLOCKS];
    int s1 = (blockIdx.x + 1 < NBKT) ? bh2[(blockIdx.x + 1) * SCAT_BLOCKS] : N_EDGES;
    if (tid < 128) c[tid] = 0;
    __syncthreads();
    for (int i = s0 + tid; i < s1; i += 256) atomicAdd(&c[packed[i] & 127], 1);
    __syncthreads();
    if (tid < 128) rp[tid] = c[tid];
    __syncthreads();
    for (int off = 1; off < 128; off <<= 1) {
        int y = 0;
        if (tid >= off && tid < 128) y = rp[tid - off];
        __syncthreads();
        if (tid >= off && tid < 128) rp[tid] += y;
        __syncthreads();
    }
    int node = blockIdx.x * 128 + tid;
    if (tid < 128) {
        rp[tid] = s0 + rp[tid] - c[tid];   // exclusive in-bucket prefix + bucket base
        if (node < N_NODES) {
            deg[node] = c[tid];
            row_ptr[node] = rp[tid];
            int b = 63 - min(c[tid], 63);              // descending-degree bin (folded dsort hist)
            atomicAdd(&dbh[b * SORT_BLOCKS + node / SORT_CHUNK], 1);
        }
        c[tid] = 0;
    }
    if (blockIdx.x == 0 && tid == 0) row_ptr[N_NODES] = N_EDGES;
    __syncthreads();
    for (int i = s0 + tid; i < s1; i += 256) {
        int p = packed[i];
        int dl = p & 127;
        int pos = rp[dl] + atomicAdd(&c[dl], 1);
        col[pos] = p >> 7;
    }
}

// scatter; each block self-scans the full dbh[2560] in LDS (exclusive prefix); DESCENDING degree
__global__ __launch_bounds__(256) void dsort_scat_kernel(const int* __restrict__ deg, const int* __restrict__ bh,
                                                         int* __restrict__ ord) {
    __shared__ int sbh[64 * SORT_BLOCKS];
    __shared__ int ps[256];
    __shared__ int h[64];
    int tid = threadIdx.x;
    int v[10];
    int s = 0;
    #pragma unroll
    for (int k = 0; k < 10; k++) { v[k] = bh[tid * 10 + k]; s += v[k]; }
    ps[tid] = s;
    if (tid < 64) h[tid] = 0;
    __syncthreads();
    for (int off = 1; off < 256; off <<= 1) {
        int y = 0;
        if (tid >= off) y = ps[tid - off];
        __syncthreads();
        if (tid >= off) ps[tid] += y;
        __syncthreads();
    }
    int run = ps[tid] - s;
    #pragma unroll
    for (int k = 0; k < 10; k++) { sbh[tid * 10 + k] = run; run += v[k]; }
    __syncthreads();
    int start = blockIdx.x * SORT_CHUNK;
    int end = start + SORT_CHUNK; if (end > N_NODES) end = N_NODES;
    for (int i = start + tid; i < end; i += 256) {
        int b = 63 - min(deg[i], 63);
        int pos = sbh[b * SORT_BLOCKS + blockIdx.x] + atomicAdd(&h[b], 1);
        ord[pos] = i;
    }
}

#define ACC4(u) { a0 += bf2f(u.x); a1 += bf2f(u.y); a2 += bf2f(u.z); a3 += bf2f(u.w); }

// ---------------- layer-1 agg: mean of xsrc[j,:] -> aggx[i,:]; 16 lanes/node ----------------
__global__ __launch_bounds__(256) void agg64_kernel(const unsigned short* __restrict__ xsrc,
                                                    unsigned short* __restrict__ aggx,
                                                    const int* __restrict__ row_ptr, const int* __restrict__ col,
                                                    const int* __restrict__ ord) {
    int tid = threadIdx.x;
    int slot = blockIdx.x * 16 + (tid >> 4);
    if (slot >= N_NODES) return;
    int i = ord[slot];
    int f0 = (tid & 15) * 4;
    int s = row_ptr[i], e = row_ptr[i + 1];
    float a0 = 0.f, a1 = 0.f, a2 = 0.f, a3 = 0.f;
    int t = s;
    while (t + 7 < e) {
        int j0 = col[t], j1 = col[t + 1], j2 = col[t + 2], j3 = col[t + 3];
        int j4 = col[t + 4], j5 = col[t + 5], j6 = col[t + 6], j7 = col[t + 7];
        ushort4 u0 = *(const ushort4*)(xsrc + (size_t)j0 * 64 + f0);
        ushort4 u1 = *(const ushort4*)(xsrc + (size_t)j1 * 64 + f0);
        ushort4 u2 = *(const ushort4*)(xsrc + (size_t)j2 * 64 + f0);
        ushort4 u3 = *(const ushort4*)(xsrc + (size_t)j3 * 64 + f0);
        ushort4 u4 = *(const ushort4*)(xsrc + (size_t)j4 * 64 + f0);
        ushort4 u5 = *(const ushort4*)(xsrc + (size_t)j5 * 64 + f0);
        ushort4 u6 = *(const ushort4*)(xsrc + (size_t)j6 * 64 + f0);
        ushort4 u7 = *(const ushort4*)(xsrc + (size_t)j7 * 64 + f0);
        ACC4(u0) ACC4(u1) ACC4(u2) ACC4(u3) ACC4(u4) ACC4(u5) ACC4(u6) ACC4(u7)
        t += 8;
    }
    if (t + 3 < e) {
        int j0 = col[t], j1 = col[t + 1], j2 = col[t + 2], j3 = col[t + 3];
        ushort4 u0 = *(const ushort4*)(xsrc + (size_t)j0 * 64 + f0);
        ushort4 u1 = *(const ushort4*)(xsrc + (size_t)j1 * 64 + f0);
        ushort4 u2 = *(const ushort4*)(xsrc + (size_t)j2 * 64 + f0);
        ushort4 u3 = *(const ushort4*)(xsrc + (size_t)j3 * 64 + f0);
        ACC4(u0) ACC4(u1) ACC4(u2) ACC4(u3)
        t += 4;
    }
    if (t + 1 < e) {
        int j0 = col[t], j1 = col[t + 1];
        ushort4 u0 = *(const ushort4*)(xsrc + (size_t)j0 * 64 + f0);
        ushort4 u1 = *(const ushort4*)(xsrc + (size_t)j1 * 64 + f0);
        ACC4(u0) ACC4(u1)
        t += 2;
    }
    if (t < e) {
        ushort4 u0 = *(const ushort4*)(xsrc + (size_t)col[t] * 64 + f0);
        ACC4(u0)
    }
    float di = 1.0f / fmaxf((float)(e - s), 1.0f);
    ushort4 o;
    o.x = f2bf(a0 * di); o.y = f2bf(a1 * di); o.z = f2bf(a2 * di); o.w = f2bf(a3 * di);
    *(ushort4*)(aggx + (size_t)i * 64 + f0) = o;
}

// ---------------- layers 2/3 agg: mean of hsrc[j,:] -> aggh[i,:]; 32 lanes/node ----------------
__global__ __launch_bounds__(256) void agg128_kernel(const unsigned short* __restrict__ hsrc,
                                                     unsigned short* __restrict__ aggh,
                                                     const int* __restrict__ row_ptr, const int* __restrict__ col,
                                                     const int* __restrict__ ord) {
    int tid = threadIdx.x;
    int slot = blockIdx.x * 8 + (tid >> 5);
    if (slot >= N_NODES) return;
    int i = ord[slot];
    int f0 = (tid & 31) * 4;
    int s = row_ptr[i], e = row_ptr[i + 1];
    float a0 = 0.f, a1 = 0.f, a2 = 0.f, a3 = 0.f;
    int t = s;
    while (t + 7 < e) {
        int j0 = col[t], j1 = col[t + 1], j2 = col[t + 2], j3 = col[t + 3];
        int j4 = col[t + 4], j5 = col[t + 5], j6 = col[t + 6], j7 = col[t + 7];
        ushort4 u0 = *(const ushort4*)(hsrc + (size_t)j0 * 128 + f0);
        ushort4 u1 = *(const ushort4*)(hsrc + (size_t)j1 * 128 + f0);
        ushort4 u2 = *(const ushort4*)(hsrc + (size_t)j2 * 128 + f0);
        ushort4 u3 = *(const ushort4*)(hsrc + (size_t)j3 * 128 + f0);
        ushort4 u4 = *(const ushort4*)(hsrc + (size_t)j4 * 128 + f0);
        ushort4 u5 = *(const ushort4*)(hsrc + (size_t)j5 * 128 + f0);
        ushort4 u6 = *(const ushort4*)(hsrc + (size_t)j6 * 128 + f0);
        ushort4 u7 = *(const ushort4*)(hsrc + (size_t)j7 * 128 + f0);
        ACC4(u0) ACC4(u1) ACC4(u2) ACC4(u3) ACC4(u4) ACC4(u5) ACC4(u6) ACC4(u7)
        t += 8;
    }
    if (t + 3 < e) {
        int j0 = col[t], j1 = col[t + 1], j2 = col[t + 2], j3 = col[t + 3];
        ushort4 u0 = *(const ushort4*)(hsrc + (size_t)j0 * 128 + f0);
        ushort4 u1 = *(const ushort4*)(hsrc + (size_t)j1 * 128 + f0);
        ushort4 u2 = *(const ushort4*)(hsrc + (size_t)j2 * 128 + f0);
        ushort4 u3 = *(const ushort4*)(hsrc + (size_t)j3 * 128 + f0);
        ACC4(u0) ACC4(u1) ACC4(u2) ACC4(u3)
        t += 4;
    }
    if (t + 1 < e) {
        int j0 = col[t], j1 = col[t + 1];
        ushort4 u0 = *(const ushort4*)(hsrc + (size_t)j0 * 128 + f0);
        ushort4 u1 = *(const ushort4*)(hsrc + (size_t)j1 * 128 + f0);
        ACC4(u0) ACC4(u1)
        t += 2;
    }
    if (t < e) {
        ushort4 u0 = *(const ushort4*)(hsrc + (size_t)col[t] * 128 + f0);
        ACC4(u0)
    }
    float di = 1.0f / fmaxf((float)(e - s), 1.0f);
    ushort4 o;
    o.x = f2bf(a0 * di); o.y = f2bf(a1 * di); o.z = f2bf(a2 * di); o.w = f2bf(a3 * di);
    *(ushort4*)(aggh + (size_t)i * 128 + f0) = o;
}

// ---------------- layer-1 fused GEMM+LN (weight-stationary, A streamed from global) ----------------
__global__ __launch_bounds__(512) void mgemm1_ln_kernel(const unsigned short* __restrict__ Ax,
                                                        const unsigned short* __restrict__ Aa,
                                                        const unsigned short* __restrict__ Bt,
                                                        const float* __restrict__ b1, const float* __restrict__ ln_g,
                                                        const float* __restrict__ ln_b, const float* __restrict__ bres,
                                                        unsigned short* __restrict__ hsrc) {
    __shared__ unsigned short Bs[32768];   // 256 n-rows x 128 k (rows 0..127 = T, 128..255 = Wres)
    int tid = threadIdx.x;
    int wave = tid >> 6, lane = tid & 63;
    int lm = lane & 15, lk = (lane >> 4) * 8;

    #pragma unroll
    for (int rnd = 0; rnd < 8; rnd++) {
        int Lb = rnd * 8192 + tid * 16;           // linear LDS byte offset (uniform + lane*16)
        int row = Lb >> 8;                        // 256B rows
        int sb = (Lb & 255) ^ ((row & 7) << 4);   // pre-swizzled source byte-in-row
        gld_lds16(Bt + (size_t)row * 128 + (sb >> 1), &Bs[Lb >> 1]);
    }
    __syncthreads();

    int strip = blockIdx.x * 8 + wave;
    if (strip >= NSTRIPS) return;
    int m0 = strip * 16;

    float4v accT[8], accR[8];
    #pragma unroll
    for (int j = 0; j < 8; j++) { accT[j] = (float4v)0.f; accR[j] = (float4v)0.f; }

    const unsigned short* arx = Ax + (size_t)(m0 + lm) * 64 + lk;
    const unsigned short* ara = Aa + (size_t)(m0 + lm) * 64 + lk;
    #pragma unroll
    for (int k0 = 0; k0 < 128; k0 += 32) {
        short8v af = (k0 < 64) ? *(const short8v*)(arx + k0) : *(const short8v*)(ara + (k0 - 64));
        short8v bf[8];
        #pragma unroll
        for (int j = 0; j < 8; j++)
            bf[j] = *(const short8v*)&Bs[SWZ128(j * 16 + lm, k0 + lk)];
        #pragma unroll
        for (int j = 0; j < 8; j++)
            accT[j] = __builtin_amdgcn_mfma_f32_16x16x32_bf16(af, bf[j], accT[j], 0, 0, 0);
        if (k0 < 64) {                            // residual path only has k<64 support
            short8v bg[8];
            #pragma unroll
            for (int j = 0; j < 8; j++)
                bg[j] = *(const short8v*)&Bs[SWZ128(128 + j * 16 + lm, k0 + lk)];
            #pragma unroll
            for (int j = 0; j < 8; j++)
                accR[j] = __builtin_amdgcn_mfma_f32_16x16x32_bf16(af, bg[j], accR[j], 0, 0, 0);
        }
    }

    float b1v[8], gv[8], bbv[8], brv[8];
    #pragma unroll
    for (int j = 0; j < 8; j++) {
        int cc = j * 16 + lm;
        b1v[j] = b1[cc]; gv[j] = ln_g[cc]; bbv[j] = ln_b[cc]; brv[j] = bres[cc];
    }
    int q4 = lane >> 4;
    #pragma unroll
    for (int r = 0; r < 4; r++) {
        float sp = 0.f, sq = 0.f;
        #pragma unroll
        for (int j = 0; j < 8; j++) {
            float tv = accT[j][r] + b1v[j];
            sp += tv; sq += tv * tv;
        }
        #pragma unroll
        for (int off = 1; off < 16; off <<= 1) {
            sp += __shfl_xor(sp, off);
            sq += __shfl_xor(sq, off);
        }
        float mu = sp * (1.f / 128.f);
        float var = sq * (1.f / 128.f) - mu * mu;
        float rstd = rsqrtf(var + 1e-5f);
        int gm = m0 + q4 * 4 + r;
        #pragma unroll
        for (int j = 0; j < 8; j++) {
            float tv = accT[j][r] + b1v[j];
            float y = fmaxf((tv - mu) * rstd * gv[j] + bbv[j], 0.f) + accR[j][r] + brv[j];
            hsrc[(size_t)gm * 128 + j * 16 + lm] = f2bf(y);
        }
    }
}

// ---------------- layer-2 GEMM: hsrc = relu([hsrc|aggh] @ Bt2^T + b2), in-place safe ----------------
__global__ __launch_bounds__(512) void mgemm_kernel(const unsigned short* __restrict__ Ah,
                                                    const unsigned short* __restrict__ Aa,
                                                    const unsigned short* __restrict__ Bt,
                                                    const float* __restrict__ bias,
                                                    unsigned short* __restrict__ C) {
    __shared__ unsigned short Bs[32768];   // 128 n-rows x 256 k
    int tid = threadIdx.x;
    int wave = tid >> 6, lane = tid & 63;
    int lm = lane & 15, lk = (lane >> 4) * 8;

    #pragma unroll
    for (int rnd = 0; rnd < 8; rnd++) {
        int Lb = rnd * 8192 + tid * 16;
        int row = Lb >> 9;                        // 512B rows
        int sb = (Lb & 511) ^ ((row & 7) << 4);
        gld_lds16(Bt + ((size_t)row << 8) + (sb >> 1), &Bs[Lb >> 1]);
    }
    __syncthreads();

    int strip = blockIdx.x * 8 + wave;
    if (strip >= NSTRIPS) return;
    int m0 = strip * 16;

    float4v acc[8];
    #pragma unroll
    for (int j = 0; j < 8; j++) acc[j] = (float4v)0.f;

    const unsigned short* arh = Ah + (size_t)(m0 + lm) * 128 + lk;
    const unsigned short* ara = Aa + (size_t)(m0 + lm) * 128 + lk;
    #pragma unroll
    for (int k0 = 0; k0 < 256; k0 += 32) {
        short8v af = (k0 < 128) ? *(const short8v*)(arh + k0) : *(const short8v*)(ara + (k0 - 128));
        short8v bf[8];
        #pragma unroll
        for (int j = 0; j < 8; j++)
            bf[j] = *(const short8v*)&Bs[SWZ256(j * 16 + lm, k0 + lk)];
        #pragma unroll
        for (int j = 0; j < 8; j++)
            acc[j] = __builtin_amdgcn_mfma_f32_16x16x32_bf16(af, bf[j], acc[j], 0, 0, 0);
    }

    int q4 = lane >> 4;
    #pragma unroll
    for (int j = 0; j < 8; j++) {
        int cc = j * 16 + lm;
        float bv = bias[cc];
        #pragma unroll
        for (int r = 0; r < 4; r++) {
            int m = m0 + q4 * 4 + r;
            C[(size_t)m * 128 + cc] = f2bf(fmaxf(acc[j][r] + bv, 0.f));
        }
    }
}

// ---------------- layer-3 fused GEMM+pq (h3 never stored) ----------------
__global__ __launch_bounds__(512) void mgemm_pq_kernel(const unsigned short* __restrict__ Ah,
                                                       const unsigned short* __restrict__ Aa,
                                                       const unsigned short* __restrict__ Bt,
                                                       const float* __restrict__ bias,
                                                       const float* __restrict__ Wl4, const float* __restrict__ Wr4,
                                                       const float* __restrict__ b4,
                                                       float* __restrict__ p, float* __restrict__ q) {
    __shared__ unsigned short Bs[32768];   // 128 n-rows x 256 k
    int tid = threadIdx.x;
    int wave = tid >> 6, lane = tid & 63;
    int lm = lane & 15, lk = (lane >> 4) * 8;

    #pragma unroll
    for (int rnd = 0; rnd < 8; rnd++) {
        int Lb = rnd * 8192 + tid * 16;
        int row = Lb >> 9;
        int sb = (Lb & 511) ^ ((row & 7) << 4);
        gld_lds16(Bt + ((size_t)row << 8) + (sb >> 1), &Bs[Lb >> 1]);
    }
    __syncthreads();

    int strip = blockIdx.x * 8 + wave;
    if (strip >= NSTRIPS) return;
    int m0 = strip * 16;

    float4v acc[8];
    #pragma unroll
    for (int j = 0; j < 8; j++) acc[j] = (float4v)0.f;

    const unsigned short* arh = Ah + (size_t)(m0 + lm) * 128 + lk;
    const unsigned short* ara = Aa + (size_t)(m0 + lm) * 128 + lk;
    #pragma unroll
    for (int k0 = 0; k0 < 256; k0 += 32) {
        short8v af = (k0 < 128) ? *(const short8v*)(arh + k0) : *(const short8v*)(ara + (k0 - 128));
        short8v bf[8];
        #pragma unroll
        for (int j = 0; j < 8; j++)
            bf[j] = *(const short8v*)&Bs[SWZ256(j * 16 + lm, k0 + lk)];
        #pragma unroll
        for (int j = 0; j < 8; j++)
            acc[j] = __builtin_amdgcn_mfma_f32_16x16x32_bf16(af, bf[j], acc[j], 0, 0, 0);
    }

    float b3v[8], wlv[8], wrv[8];
    #pragma unroll
    for (int j = 0; j < 8; j++) {
        int cc = j * 16 + lm;
        b3v[j] = bias[cc]; wlv[j] = Wl4[cc]; wrv[j] = Wr4[cc];
    }
    float b4v = b4[0];
    int q4 = lane >> 4;
    #pragma unroll
    for (int r = 0; r < 4; r++) {
        float pp = 0.f, qq = 0.f;
        #pragma unroll
        for (int j = 0; j < 8; j++) {
            float hv = fmaxf(acc[j][r] + b3v[j], 0.f);
            pp += hv * wlv[j]; qq += hv * wrv[j];
        }
        #pragma unroll
        for (int off = 1; off < 16; off <<= 1) {
            pp += __shfl_xor(pp, off);
            qq += __shfl_xor(qq, off);
        }
        if (lm == 0) {
            int m = m0 + q4 * 4 + r;
            p[m] = pp;
            q[m] = qq + b4v;
        }
    }
}

__global__ __launch_bounds__(256) void final_kernel(const float* __restrict__ p, const float* __restrict__ q,
                                                    const int* __restrict__ row_ptr, const int* __restrict__ col,
                                                    float* __restrict__ out) {
    int i = blockIdx.x * 256 + threadIdx.x;   // original node id
    if (i >= N_NODES) return;
    int s = row_ptr[i], e = row_ptr[i + 1];
    float acc = 0.f;
    int t = s;
    for (; t + 7 < e; t += 8)
        acc += p[col[t]] + p[col[t + 1]] + p[col[t + 2]] + p[col[t + 3]]
             + p[col[t + 4]] + p[col[t + 5]] + p[col[t + 6]] + p[col[t + 7]];
    for (; t < e; t++) acc += p[col[t]];
    float di = 1.0f / fmaxf((float)(e - s), 1.0f);
    out[i] = acc * di + q[i];
}

// ---------------- launch ----------------

extern "C" void kernel_launch(void* const* d_in, const int* in_sizes, int n_in,
                              void* d_out, int out_size, void* d_ws, size_t ws_size,
                              hipStream_t stream) {
    const float* x    = (const float*)d_in[0];
    const int*   ei   = (const int*)d_in[1];
    const float* Wl1  = (const float*)d_in[2];
    const float* Wr1  = (const float*)d_in[3];
    const float* b1   = (const float*)d_in[4];
    const float* ln_g = (const float*)d_in[5];
    const float* ln_b = (const float*)d_in[6];
    const float* Wres = (const float*)d_in[7];
    const float* bres = (const float*)d_in[8];
    const float* Wl2  = (const float*)d_in[9];
    const float* Wr2  = (const float*)d_in[10];
    const float* b2   = (const float*)d_in[11];
    const float* Wl3  = (const float*)d_in[12];
    const float* Wr3  = (const float*)d_in[13];
    const float* b3   = (const float*)d_in[14];
    const float* Wl4  = (const float*)d_in[15];
    const float* Wr4  = (const float*)d_in[16];
    const float* b4   = (const float*)d_in[17];
    float* out = (float*)d_out;

    char* w = (char*)d_ws;
    size_t off = 0;
    auto alloc = [&](size_t bytes) -> void* {
        off = (off + 255) & ~(size_t)255;
        void* pp = w + off;
        off += bytes;
        return pp;
    };

    int* dbh      = (int*)alloc(64 * SORT_BLOCKS * 4);  // zeroed by memset
    int* bh2      = (int*)alloc(BH2_N * 4);
    int* bsum     = (int*)alloc(1024);
    int* deg      = (int*)alloc(N_NODES * 4);
    int* row_ptr  = (int*)alloc((N_NODES + 1) * 4);
    int* col      = (int*)alloc(N_EDGES * 4);
    int* ord      = (int*)alloc(N_NODES * 4);       // sorted slot -> original node (desc degree)
    unsigned short* Bt1  = (unsigned short*)alloc(256 * 128 * 2);
    unsigned short* Bt2  = (unsigned short*)alloc(128 * 256 * 2);
    unsigned short* Bt3  = (unsigned short*)alloc(128 * 256 * 2);
    unsigned short* xsrc = (unsigned short*)alloc((size_t)N_NODES * 64 * 2);   // x bf16 (compact)
    unsigned short* aggx = (unsigned short*)alloc((size_t)N_NODES * 64 * 2);   // agg(x)
    unsigned short* hsrc = (unsigned short*)alloc((size_t)N_NODES * 128 * 2);  // h bf16 (compact)
    unsigned short* aggh = (unsigned short*)alloc((size_t)N_NODES * 128 * 2);  // agg(h)
    int*   packed  = (int*)alloc((size_t)N_EDGES * 4);   // CSR build scratch
    float* p       = (float*)alloc(N_NODES * 4);
    float* q       = (float*)alloc(N_NODES * 4);
    (void)ws_size; (void)n_in; (void)in_sizes; (void)out_size;

    const int NB = (N_NODES + 255) / 256;

    // --- zero dsort hist, then mega front-end: wprep | edge hist -> bh2 | x->bf16 ---
    hipMemsetAsync(dbh, 0, 64 * SORT_BLOCKS * 4, stream);
    mega0_kernel<<<WPREP_BLOCKS + SCAT_BLOCKS + XBF_BLOCKS, 256, 0, stream>>>(
        Wr1, Wl1, Wres, Wl2, Wr2, Wl3, Wr3, Bt1, Bt2, Bt3, ei, bh2, x, xsrc);

    // --- CSR build (LDS-privatized scatter; bh2 matrix scan gives per-(bucket,block) bases) ---
    gscan_a_kernel<<<BHB, 256, 0, stream>>>(bh2, bsum, BH2_N);
    gscan_c_kernel<<<BHB, 256, 0, stream>>>(bh2, bsum, BHB, BH2_N);
    bkt_scatter2_kernel<<<SCAT_BLOCKS, 256, 0, stream>>>(ei, bh2, packed);
    bkt_build_kernel<<<NBKT, 256, 0, stream>>>(packed, bh2, deg, row_ptr, col, dbh);
    dsort_scat_kernel<<<SORT_BLOCKS, 256, 0, stream>>>(deg, dbh, ord);

    // --- layer 1: agg(x) -> aggx; fused GEMM+LN -> hsrc ---
    agg64_kernel<<<(N_NODES + 15) / 16, 256, 0, stream>>>(xsrc, aggx, row_ptr, col, ord);
    mgemm1_ln_kernel<<<GEMM_BLOCKS, 512, 0, stream>>>(xsrc, aggx, Bt1, b1, ln_g, ln_b, bres, hsrc);

    // --- layer 2: agg(h) -> aggh; GEMM [h|aggh] -> hsrc (bias+relu, in-place) ---
    agg128_kernel<<<(N_NODES + 7) / 8, 256, 0, stream>>>(hsrc, aggh, row_ptr, col, ord);
    mgemm_kernel<<<GEMM_BLOCKS, 512, 0, stream>>>(hsrc, aggh, Bt2, b2, hsrc);

    // --- layer 3: agg(h) -> aggh; fused GEMM+pq -> p, q (h3 never stored) ---
    agg128_kernel<<<(N_NODES + 7) / 8, 256, 0, stream>>>(hsrc, aggh, row_ptr, col, ord);
    mgemm_pq_kernel<<<GEMM_BLOCKS, 512, 0, stream>>>(hsrc, aggh, Bt3, b3, Wl4, Wr4, b4, p, q);

    // --- final ---
    final_kernel<<<NB, 256, 0, stream>>>(p, q, row_ptr, col, out);
}

// Round 8
// 365.823 us; speedup vs baseline: 2.1700x; 1.1968x over previous
//
#include <hip/hip_runtime.h>
#include <hip/hip_bf16.h>

#define N_NODES 100000
#define N_EDGES 1600000

#define NBKT 782                 // ceil(N_NODES / 128)
#define SCAT_BLOCKS 240
#define BKT_CHUNK 6667           // ceil(N_EDGES / 240)

#define WPREP_BLOCKS 384
#define XBF_BLOCKS 6250          // N_NODES*16/256

#define SORT_BLOCKS 40
#define SORT_CHUNK 2560          // 40 * 2560 >= 100000; multiple of 128 so each bkt_build block is one chunk
#define BH2_N (NBKT * SCAT_BLOCKS)   // 187680
#define BHB ((BH2_N + 1023) / 1024)  // 184

#define NSTRIPS 6250             // N_NODES / 16 (exact)
#define GEMM_BLOCKS 782          // ceil(NSTRIPS / 8 waves)

typedef __attribute__((ext_vector_type(8))) short short8v;
typedef __attribute__((ext_vector_type(4))) float float4v;

__device__ __forceinline__ unsigned short f2bf(float f) {
    unsigned int u = __float_as_uint(f);
    u = (u + 0x7FFFu + ((u >> 16) & 1u)) >> 16;   // RTNE
    return (unsigned short)u;
}
__device__ __forceinline__ float bf2f(unsigned short b) {
    return __uint_as_float((unsigned int)b << 16);
}

// async global->LDS, 16B per lane. LDS dest must be linear (wave base + lane*16);
// swizzle goes on the GLOBAL source address (rule #21: both-sides-or-neither).
typedef __attribute__((address_space(1))) const unsigned int gld_g_t;
typedef __attribute__((address_space(3))) unsigned int gld_l_t;
__device__ __forceinline__ void gld_lds16(const void* g, void* l) {
    __builtin_amdgcn_global_load_lds((gld_g_t*)g, (gld_l_t*)l, 16, 0, 0);
}

// swizzled ds_read index (shorts): XOR byte ^= ((row&7)<<4) within a row
#define SWZ128(row, ksh) ((row) * 128 + ((ksh) ^ (((row) & 7) << 3)))   // 128-short rows
#define SWZ256(row, ksh) ((row) * 256 + ((ksh) ^ (((row) & 7) << 3)))   // 256-short rows

// ---------------- mega front-end: wprep (0..383) | edge histogram -> bh2 (384..623) | x->bf16 (624..) ----------------
__global__ __launch_bounds__(256) void mega0_kernel(const float* __restrict__ Wr1, const float* __restrict__ Wl1,
                                                    const float* __restrict__ Wres,
                                                    const float* __restrict__ Wl2, const float* __restrict__ Wr2,
                                                    const float* __restrict__ Wl3, const float* __restrict__ Wr3,
                                                    unsigned short* __restrict__ Bt1,
                                                    unsigned short* __restrict__ Bt2,
                                                    unsigned short* __restrict__ Bt3,
                                                    const int* __restrict__ ei, int* __restrict__ bh2,
                                                    const float* __restrict__ x, unsigned short* __restrict__ xsrc) {
    __shared__ int h[NBKT];
    int tid = threadIdx.x;
    int bid = blockIdx.x;
    if (bid < WPREP_BLOCKS) {
        int idx = bid * 256 + tid;
        int seg = idx >> 15;          // 32768 elements per segment
        int loc = idx & 32767;
        if (seg == 0) {
            int n = loc >> 7;
            int k = loc & 127;
            float v;
            if (n < 128) v = (k < 64) ? Wr1[k * 128 + n] : Wl1[(k - 64) * 128 + n];
            else         v = (k < 64) ? Wres[k * 128 + (n - 128)] : 0.f;
            Bt1[loc] = f2bf(v);
        } else if (seg == 1) {
            int n = loc >> 8;
            int k = loc & 255;
            float v = (k < 128) ? Wr2[k * 128 + n] : Wl2[(k - 128) * 128 + n];
            Bt2[loc] = f2bf(v);
        } else {
            int n = loc >> 8;
            int k = loc & 255;
            float v = (k < 128) ? Wr3[k * 128 + n] : Wl3[(k - 128) * 128 + n];
            Bt3[loc] = f2bf(v);
        }
    } else if (bid < WPREP_BLOCKS + SCAT_BLOCKS) {
        int hb = bid - WPREP_BLOCKS;
        for (int i = tid; i < NBKT; i += 256) h[i] = 0;
        __syncthreads();
        int start = hb * BKT_CHUNK;
        int end = start + BKT_CHUNK; if (end > N_EDGES) end = N_EDGES;
        for (int i = start + tid; i < end; i += 256) {
            int d = ei[N_EDGES + i];
            atomicAdd(&h[d >> 7], 1);
        }
        __syncthreads();
        for (int i = tid; i < NBKT; i += 256) bh2[i * SCAT_BLOCKS + hb] = h[i];
    } else {
        int idx = (bid - WPREP_BLOCKS - SCAT_BLOCKS) * 256 + tid;   // one float4 per thread
        if (idx < N_NODES * 16) {
            int node = idx >> 4;
            int f0 = (idx & 15) * 4;
            float4 v = *(const float4*)(x + (size_t)idx * 4);
            ushort4 o;
            o.x = f2bf(v.x); o.y = f2bf(v.y); o.z = f2bf(v.z); o.w = f2bf(v.w);
            *(ushort4*)(xsrc + (size_t)node * 64 + f0) = o;
        }
    }
}

__global__ __launch_bounds__(256) void gscan_a_kernel(const int* __restrict__ in, int* __restrict__ bsum, int n) {
    __shared__ int lds[256];
    int tid = threadIdx.x;
    int base = blockIdx.x * 1024 + tid * 4;
    int s = 0;
    #pragma unroll
    for (int i = 0; i < 4; i++) s += (base + i < n) ? in[base + i] : 0;
    lds[tid] = s;
    __syncthreads();
    for (int off = 128; off; off >>= 1) {
        if (tid < off) lds[tid] += lds[tid + off];
        __syncthreads();
    }
    if (tid == 0) bsum[blockIdx.x] = lds[0];
}

// in-place exclusive scan apply; each block self-scans bsum (<=256 entries) in LDS
__global__ __launch_bounds__(256) void gscan_c_kernel(int* __restrict__ data, const int* __restrict__ bsum,
                                                      int nb, int n) {
    __shared__ int sb[256];
    __shared__ int lds[256];
    int tid = threadIdx.x;
    sb[tid] = (tid < nb) ? bsum[tid] : 0;
    __syncthreads();
    for (int off = 1; off < 256; off <<= 1) {
        int y = 0;
        if (tid >= off) y = sb[tid - off];
        __syncthreads();
        if (tid >= off) sb[tid] += y;
        __syncthreads();
    }
    int blockbase = (blockIdx.x == 0) ? 0 : sb[blockIdx.x - 1];

    int base = blockIdx.x * 1024 + tid * 4;
    int v[4];
    int s = 0;
    #pragma unroll
    for (int i = 0; i < 4; i++) {
        v[i] = (base + i < n) ? data[base + i] : 0;
        s += v[i];
    }
    lds[tid] = s;
    __syncthreads();
    for (int off = 1; off < 256; off <<= 1) {
        int y = 0;
        if (tid >= off) y = lds[tid - off];
        __syncthreads();
        if (tid >= off) lds[tid] += y;
        __syncthreads();
    }
    int run = blockbase + lds[tid] - s;
    #pragma unroll
    for (int i = 0; i < 4; i++) {
        if (base + i < n) data[base + i] = run;
        run += v[i];
    }
}

// scatter with LDS-privatized counters + precomputed per-(bucket,block) bases (bh2 scanned)
__global__ __launch_bounds__(256) void bkt_scatter2_kernel(const int* __restrict__ ei, const int* __restrict__ bh2,
                                                           int* __restrict__ packed) {
    __shared__ int h[NBKT];
    __shared__ int base[NBKT];
    int tid = threadIdx.x;
    for (int i = tid; i < NBKT; i += 256) { h[i] = 0; base[i] = bh2[i * SCAT_BLOCKS + blockIdx.x]; }
    __syncthreads();
    int start = blockIdx.x * BKT_CHUNK;
    int end = start + BKT_CHUNK; if (end > N_EDGES) end = N_EDGES;
    for (int i = start + tid; i < end; i += 256) {
        int s = ei[i];
        int d = ei[N_EDGES + i];
        int b = d >> 7;
        int pos = base[b] + atomicAdd(&h[b], 1);
        packed[pos] = (s << 7) | (d & 127);
    }
}

// merged: per-bucket degree count + LDS scan -> deg[], row_ptr[]; LDS-privatized dsort hist; fill col.
__global__ __launch_bounds__(256) void bkt_build_kernel(const int* __restrict__ packed, const int* __restrict__ bh2,
                                                        int* __restrict__ deg, int* __restrict__ row_ptr,
                                                        int* __restrict__ col, int* __restrict__ dbh) {
    __shared__ int c[128];
    __shared__ int rp[128];
    __shared__ int h64[64];
    int tid = threadIdx.x;
    int s0 = bh2[blockIdx.x * SCAT_BLOCKS];
    int s1 = (blockIdx.x + 1 < NBKT) ? bh2[(blockIdx.x + 1) * SCAT_BLOCKS] : N_EDGES;
    if (tid < 128) c[tid] = 0;
    if (tid < 64) h64[tid] = 0;
    __syncthreads();
    for (int i = s0 + tid; i < s1; i += 256) atomicAdd(&c[packed[i] & 127], 1);
    __syncthreads();
    if (tid < 128) rp[tid] = c[tid];
    __syncthreads();
    for (int off = 1; off < 128; off <<= 1) {
        int y = 0;
        if (tid >= off && tid < 128) y = rp[tid - off];
        __syncthreads();
        if (tid >= off && tid < 128) rp[tid] += y;
        __syncthreads();
    }
    int node = blockIdx.x * 128 + tid;
    if (tid < 128) {
        int myDeg = c[tid];
        rp[tid] = s0 + rp[tid] - myDeg;   // exclusive in-bucket prefix + bucket base
        if (node < N_NODES) {
            deg[node] = myDeg;
            row_ptr[node] = rp[tid];
            atomicAdd(&h64[63 - min(myDeg, 63)], 1);   // LDS-privatized (rule: hot-bin hist -> LDS first)
        }
        c[tid] = 0;
    }
    if (blockIdx.x == 0 && tid == 0) row_ptr[N_NODES] = N_EDGES;
    __syncthreads();
    // flush: <=64 global atomics per block; all of this block's nodes share one dsort chunk (2560 = 20*128)
    if (tid < 64 && h64[tid]) atomicAdd(&dbh[tid * SORT_BLOCKS + blockIdx.x / 20], h64[tid]);
    for (int i = s0 + tid; i < s1; i += 256) {
        int p = packed[i];
        int dl = p & 127;
        int pos = rp[dl] + atomicAdd(&c[dl], 1);
        col[pos] = p >> 7;
    }
}

// scatter; each block self-scans the full dbh[2560] in LDS (exclusive prefix); DESCENDING degree
__global__ __launch_bounds__(256) void dsort_scat_kernel(const int* __restrict__ deg, const int* __restrict__ bh,
                                                         int* __restrict__ ord) {
    __shared__ int sbh[64 * SORT_BLOCKS];
    __shared__ int ps[256];
    __shared__ int h[64];
    int tid = threadIdx.x;
    int v[10];
    int s = 0;
    #pragma unroll
    for (int k = 0; k < 10; k++) { v[k] = bh[tid * 10 + k]; s += v[k]; }
    ps[tid] = s;
    if (tid < 64) h[tid] = 0;
    __syncthreads();
    for (int off = 1; off < 256; off <<= 1) {
        int y = 0;
        if (tid >= off) y = ps[tid - off];
        __syncthreads();
        if (tid >= off) ps[tid] += y;
        __syncthreads();
    }
    int run = ps[tid] - s;
    #pragma unroll
    for (int k = 0; k < 10; k++) { sbh[tid * 10 + k] = run; run += v[k]; }
    __syncthreads();
    int start = blockIdx.x * SORT_CHUNK;
    int end = start + SORT_CHUNK; if (end > N_NODES) end = N_NODES;
    for (int i = start + tid; i < end; i += 256) {
        int b = 63 - min(deg[i], 63);
        int pos = sbh[b * SORT_BLOCKS + blockIdx.x] + atomicAdd(&h[b], 1);
        ord[pos] = i;
    }
}

#define ACC4(u) { a0 += bf2f(u.x); a1 += bf2f(u.y); a2 += bf2f(u.z); a3 += bf2f(u.w); }

// ---------------- layer-1 agg: mean of xsrc[j,:] -> aggx[i,:]; 16 lanes/node ----------------
__global__ __launch_bounds__(256) void agg64_kernel(const unsigned short* __restrict__ xsrc,
                                                    unsigned short* __restrict__ aggx,
                                                    const int* __restrict__ row_ptr, const int* __restrict__ col,
                                                    const int* __restrict__ ord) {
    int tid = threadIdx.x;
    int slot = blockIdx.x * 16 + (tid >> 4);
    if (slot >= N_NODES) return;
    int i = ord[slot];
    int f0 = (tid & 15) * 4;
    int s = row_ptr[i], e = row_ptr[i + 1];
    float a0 = 0.f, a1 = 0.f, a2 = 0.f, a3 = 0.f;
    int t = s;
    while (t + 7 < e) {
        int j0 = col[t], j1 = col[t + 1], j2 = col[t + 2], j3 = col[t + 3];
        int j4 = col[t + 4], j5 = col[t + 5], j6 = col[t + 6], j7 = col[t + 7];
        ushort4 u0 = *(const ushort4*)(xsrc + (size_t)j0 * 64 + f0);
        ushort4 u1 = *(const ushort4*)(xsrc + (size_t)j1 * 64 + f0);
        ushort4 u2 = *(const ushort4*)(xsrc + (size_t)j2 * 64 + f0);
        ushort4 u3 = *(const ushort4*)(xsrc + (size_t)j3 * 64 + f0);
        ushort4 u4 = *(const ushort4*)(xsrc + (size_t)j4 * 64 + f0);
        ushort4 u5 = *(const ushort4*)(xsrc + (size_t)j5 * 64 + f0);
        ushort4 u6 = *(const ushort4*)(xsrc + (size_t)j6 * 64 + f0);
        ushort4 u7 = *(const ushort4*)(xsrc + (size_t)j7 * 64 + f0);
        ACC4(u0) ACC4(u1) ACC4(u2) ACC4(u3) ACC4(u4) ACC4(u5) ACC4(u6) ACC4(u7)
        t += 8;
    }
    if (t + 3 < e) {
        int j0 = col[t], j1 = col[t + 1], j2 = col[t + 2], j3 = col[t + 3];
        ushort4 u0 = *(const ushort4*)(xsrc + (size_t)j0 * 64 + f0);
        ushort4 u1 = *(const ushort4*)(xsrc + (size_t)j1 * 64 + f0);
        ushort4 u2 = *(const ushort4*)(xsrc + (size_t)j2 * 64 + f0);
        ushort4 u3 = *(const ushort4*)(xsrc + (size_t)j3 * 64 + f0);
        ACC4(u0) ACC4(u1) ACC4(u2) ACC4(u3)
        t += 4;
    }
    if (t + 1 < e) {
        int j0 = col[t], j1 = col[t + 1];
        ushort4 u0 = *(const ushort4*)(xsrc + (size_t)j0 * 64 + f0);
        ushort4 u1 = *(const ushort4*)(xsrc + (size_t)j1 * 64 + f0);
        ACC4(u0) ACC4(u1)
        t += 2;
    }
    if (t < e) {
        ushort4 u0 = *(const ushort4*)(xsrc + (size_t)col[t] * 64 + f0);
        ACC4(u0)
    }
    float di = 1.0f / fmaxf((float)(e - s), 1.0f);
    ushort4 o;
    o.x = f2bf(a0 * di); o.y = f2bf(a1 * di); o.z = f2bf(a2 * di); o.w = f2bf(a3 * di);
    *(ushort4*)(aggx + (size_t)i * 64 + f0) = o;
}

// ---------------- layers 2/3 agg: mean of hsrc[j,:] -> aggh[i,:]; 32 lanes/node ----------------
__global__ __launch_bounds__(256) void agg128_kernel(const unsigned short* __restrict__ hsrc,
                                                     unsigned short* __restrict__ aggh,
                                                     const int* __restrict__ row_ptr, const int* __restrict__ col,
                                                     const int* __restrict__ ord) {
    int tid = threadIdx.x;
    int slot = blockIdx.x * 8 + (tid >> 5);
    if (slot >= N_NODES) return;
    int i = ord[slot];
    int f0 = (tid & 31) * 4;
    int s = row_ptr[i], e = row_ptr[i + 1];
    float a0 = 0.f, a1 = 0.f, a2 = 0.f, a3 = 0.f;
    int t = s;
    while (t + 7 < e) {
        int j0 = col[t], j1 = col[t + 1], j2 = col[t + 2], j3 = col[t + 3];
        int j4 = col[t + 4], j5 = col[t + 5], j6 = col[t + 6], j7 = col[t + 7];
        ushort4 u0 = *(const ushort4*)(hsrc + (size_t)j0 * 128 + f0);
        ushort4 u1 = *(const ushort4*)(hsrc + (size_t)j1 * 128 + f0);
        ushort4 u2 = *(const ushort4*)(hsrc + (size_t)j2 * 128 + f0);
        ushort4 u3 = *(const ushort4*)(hsrc + (size_t)j3 * 128 + f0);
        ushort4 u4 = *(const ushort4*)(hsrc + (size_t)j4 * 128 + f0);
        ushort4 u5 = *(const ushort4*)(hsrc + (size_t)j5 * 128 + f0);
        ushort4 u6 = *(const ushort4*)(hsrc + (size_t)j6 * 128 + f0);
        ushort4 u7 = *(const ushort4*)(hsrc + (size_t)j7 * 128 + f0);
        ACC4(u0) ACC4(u1) ACC4(u2) ACC4(u3) ACC4(u4) ACC4(u5) ACC4(u6) ACC4(u7)
        t += 8;
    }
    if (t + 3 < e) {
        int j0 = col[t], j1 = col[t + 1], j2 = col[t + 2], j3 = col[t + 3];
        ushort4 u0 = *(const ushort4*)(hsrc + (size_t)j0 * 128 + f0);
        ushort4 u1 = *(const ushort4*)(hsrc + (size_t)j1 * 128 + f0);
        ushort4 u2 = *(const ushort4*)(hsrc + (size_t)j2 * 128 + f0);
        ushort4 u3 = *(const ushort4*)(hsrc + (size_t)j3 * 128 + f0);
        ACC4(u0) ACC4(u1) ACC4(u2) ACC4(u3)
        t += 4;
    }
    if (t + 1 < e) {
        int j0 = col[t], j1 = col[t + 1];
        ushort4 u0 = *(const ushort4*)(hsrc + (size_t)j0 * 128 + f0);
        ushort4 u1 = *(const ushort4*)(hsrc + (size_t)j1 * 128 + f0);
        ACC4(u0) ACC4(u1)
        t += 2;
    }
    if (t < e) {
        ushort4 u0 = *(const ushort4*)(hsrc + (size_t)col[t] * 128 + f0);
        ACC4(u0)
    }
    float di = 1.0f / fmaxf((float)(e - s), 1.0f);
    ushort4 o;
    o.x = f2bf(a0 * di); o.y = f2bf(a1 * di); o.z = f2bf(a2 * di); o.w = f2bf(a3 * di);
    *(ushort4*)(aggh + (size_t)i * 128 + f0) = o;
}

// ---------------- layer-1 fused GEMM+LN (weight-stationary, A streamed from global) ----------------
__global__ __launch_bounds__(512) void mgemm1_ln_kernel(const unsigned short* __restrict__ Ax,
                                                        const unsigned short* __restrict__ Aa,
                                                        const unsigned short* __restrict__ Bt,
                                                        const float* __restrict__ b1, const float* __restrict__ ln_g,
                                                        const float* __restrict__ ln_b, const float* __restrict__ bres,
                                                        unsigned short* __restrict__ hsrc) {
    __shared__ unsigned short Bs[32768];   // 256 n-rows x 128 k (rows 0..127 = T, 128..255 = Wres)
    int tid = threadIdx.x;
    int wave = tid >> 6, lane = tid & 63;
    int lm = lane & 15, lk = (lane >> 4) * 8;

    #pragma unroll
    for (int rnd = 0; rnd < 8; rnd++) {
        int Lb = rnd * 8192 + tid * 16;           // linear LDS byte offset (uniform + lane*16)
        int row = Lb >> 8;                        // 256B rows
        int sb = (Lb & 255) ^ ((row & 7) << 4);   // pre-swizzled source byte-in-row
        gld_lds16(Bt + (size_t)row * 128 + (sb >> 1), &Bs[Lb >> 1]);
    }
    __syncthreads();

    int strip = blockIdx.x * 8 + wave;
    if (strip >= NSTRIPS) return;
    int m0 = strip * 16;

    float4v accT[8], accR[8];
    #pragma unroll
    for (int j = 0; j < 8; j++) { accT[j] = (float4v)0.f; accR[j] = (float4v)0.f; }

    const unsigned short* arx = Ax + (size_t)(m0 + lm) * 64 + lk;
    const unsigned short* ara = Aa + (size_t)(m0 + lm) * 64 + lk;
    #pragma unroll
    for (int k0 = 0; k0 < 128; k0 += 32) {
        short8v af = (k0 < 64) ? *(const short8v*)(arx + k0) : *(const short8v*)(ara + (k0 - 64));
        short8v bf[8];
        #pragma unroll
        for (int j = 0; j < 8; j++)
            bf[j] = *(const short8v*)&Bs[SWZ128(j * 16 + lm, k0 + lk)];
        #pragma unroll
        for (int j = 0; j < 8; j++)
            accT[j] = __builtin_amdgcn_mfma_f32_16x16x32_bf16(af, bf[j], accT[j], 0, 0, 0);
        if (k0 < 64) {                            // residual path only has k<64 support
            short8v bg[8];
            #pragma unroll
            for (int j = 0; j < 8; j++)
                bg[j] = *(const short8v*)&Bs[SWZ128(128 + j * 16 + lm, k0 + lk)];
            #pragma unroll
            for (int j = 0; j < 8; j++)
                accR[j] = __builtin_amdgcn_mfma_f32_16x16x32_bf16(af, bg[j], accR[j], 0, 0, 0);
        }
    }

    float b1v[8], gv[8], bbv[8], brv[8];
    #pragma unroll
    for (int j = 0; j < 8; j++) {
        int cc = j * 16 + lm;
        b1v[j] = b1[cc]; gv[j] = ln_g[cc]; bbv[j] = ln_b[cc]; brv[j] = bres[cc];
    }
    int q4 = lane >> 4;
    #pragma unroll
    for (int r = 0; r < 4; r++) {
        float sp = 0.f, sq = 0.f;
        #pragma unroll
        for (int j = 0; j < 8; j++) {
            float tv = accT[j][r] + b1v[j];
            sp += tv; sq += tv * tv;
        }
        #pragma unroll
        for (int off = 1; off < 16; off <<= 1) {
            sp += __shfl_xor(sp, off);
            sq += __shfl_xor(sq, off);
        }
        float mu = sp * (1.f / 128.f);
        float var = sq * (1.f / 128.f) - mu * mu;
        float rstd = rsqrtf(var + 1e-5f);
        int gm = m0 + q4 * 4 + r;
        #pragma unroll
        for (int j = 0; j < 8; j++) {
            float tv = accT[j][r] + b1v[j];
            float y = fmaxf((tv - mu) * rstd * gv[j] + bbv[j], 0.f) + accR[j][r] + brv[j];
            hsrc[(size_t)gm * 128 + j * 16 + lm] = f2bf(y);
        }
    }
}

// ---------------- layer-2 GEMM: hsrc = relu([hsrc|aggh] @ Bt2^T + b2), in-place safe ----------------
__global__ __launch_bounds__(512) void mgemm_kernel(const unsigned short* __restrict__ Ah,
                                                    const unsigned short* __restrict__ Aa,
                                                    const unsigned short* __restrict__ Bt,
                                                    const float* __restrict__ bias,
                                                    unsigned short* __restrict__ C) {
    __shared__ unsigned short Bs[32768];   // 128 n-rows x 256 k
    int tid = threadIdx.x;
    int wave = tid >> 6, lane = tid & 63;
    int lm = lane & 15, lk = (lane >> 4) * 8;

    #pragma unroll
    for (int rnd = 0; rnd < 8; rnd++) {
        int Lb = rnd * 8192 + tid * 16;
        int row = Lb >> 9;                        // 512B rows
        int sb = (Lb & 511) ^ ((row & 7) << 4);
        gld_lds16(Bt + ((size_t)row << 8) + (sb >> 1), &Bs[Lb >> 1]);
    }
    __syncthreads();

    int strip = blockIdx.x * 8 + wave;
    if (strip >= NSTRIPS) return;
    int m0 = strip * 16;

    float4v acc[8];
    #pragma unroll
    for (int j = 0; j < 8; j++) acc[j] = (float4v)0.f;

    const unsigned short* arh = Ah + (size_t)(m0 + lm) * 128 + lk;
    const unsigned short* ara = Aa + (size_t)(m0 + lm) * 128 + lk;
    #pragma unroll
    for (int k0 = 0; k0 < 256; k0 += 32) {
        short8v af = (k0 < 128) ? *(const short8v*)(arh + k0) : *(const short8v*)(ara + (k0 - 128));
        short8v bf[8];
        #pragma unroll
        for (int j = 0; j < 8; j++)
            bf[j] = *(const short8v*)&Bs[SWZ256(j * 16 + lm, k0 + lk)];
        #pragma unroll
        for (int j = 0; j < 8; j++)
            acc[j] = __builtin_amdgcn_mfma_f32_16x16x32_bf16(af, bf[j], acc[j], 0, 0, 0);
    }

    int q4 = lane >> 4;
    #pragma unroll
    for (int j = 0; j < 8; j++) {
        int cc = j * 16 + lm;
        float bv = bias[cc];
        #pragma unroll
        for (int r = 0; r < 4; r++) {
            int m = m0 + q4 * 4 + r;
            C[(size_t)m * 128 + cc] = f2bf(fmaxf(acc[j][r] + bv, 0.f));
        }
    }
}

// ---------------- layer-3 fused GEMM+pq (h3 never stored) ----------------
__global__ __launch_bounds__(512) void mgemm_pq_kernel(const unsigned short* __restrict__ Ah,
                                                       const unsigned short* __restrict__ Aa,
                                                       const unsigned short* __restrict__ Bt,
                                                       const float* __restrict__ bias,
                                                       const float* __restrict__ Wl4, const float* __restrict__ Wr4,
                                                       const float* __restrict__ b4,
                                                       float* __restrict__ p, float* __restrict__ q) {
    __shared__ unsigned short Bs[32768];   // 128 n-rows x 256 k
    int tid = threadIdx.x;
    int wave = tid >> 6, lane = tid & 63;
    int lm = lane & 15, lk = (lane >> 4) * 8;

    #pragma unroll
    for (int rnd = 0; rnd < 8; rnd++) {
        int Lb = rnd * 8192 + tid * 16;
        int row = Lb >> 9;
        int sb = (Lb & 511) ^ ((row & 7) << 4);
        gld_lds16(Bt + ((size_t)row << 8) + (sb >> 1), &Bs[Lb >> 1]);
    }
    __syncthreads();

    int strip = blockIdx.x * 8 + wave;
    if (strip >= NSTRIPS) return;
    int m0 = strip * 16;

    float4v acc[8];
    #pragma unroll
    for (int j = 0; j < 8; j++) acc[j] = (float4v)0.f;

    const unsigned short* arh = Ah + (size_t)(m0 + lm) * 128 + lk;
    const unsigned short* ara = Aa + (size_t)(m0 + lm) * 128 + lk;
    #pragma unroll
    for (int k0 = 0; k0 < 256; k0 += 32) {
        short8v af = (k0 < 128) ? *(const short8v*)(arh + k0) : *(const short8v*)(ara + (k0 - 128));
        short8v bf[8];
        #pragma unroll
        for (int j = 0; j < 8; j++)
            bf[j] = *(const short8v*)&Bs[SWZ256(j * 16 + lm, k0 + lk)];
        #pragma unroll
        for (int j = 0; j < 8; j++)
            acc[j] = __builtin_amdgcn_mfma_f32_16x16x32_bf16(af, bf[j], acc[j], 0, 0, 0);
    }

    float b3v[8], wlv[8], wrv[8];
    #pragma unroll
    for (int j = 0; j < 8; j++) {
        int cc = j * 16 + lm;
        b3v[j] = bias[cc]; wlv[j] = Wl4[cc]; wrv[j] = Wr4[cc];
    }
    float b4v = b4[0];
    int q4 = lane >> 4;
    #pragma unroll
    for (int r = 0; r < 4; r++) {
        float pp = 0.f, qq = 0.f;
        #pragma unroll
        for (int j = 0; j < 8; j++) {
            float hv = fmaxf(acc[j][r] + b3v[j], 0.f);
            pp += hv * wlv[j]; qq += hv * wrv[j];
        }
        #pragma unroll
        for (int off = 1; off < 16; off <<= 1) {
            pp += __shfl_xor(pp, off);
            qq += __shfl_xor(qq, off);
        }
        if (lm == 0) {
            int m = m0 + q4 * 4 + r;
            p[m] = pp;
            q[m] = qq + b4v;
        }
    }
}

__global__ __launch_bounds__(256) void final_kernel(const float* __restrict__ p, const float* __restrict__ q,
                                                    const int* __restrict__ row_ptr, const int* __restrict__ col,
                                                    float* __restrict__ out) {
    int i = blockIdx.x * 256 + threadIdx.x;   // original node id
    if (i >= N_NODES) return;
    int s = row_ptr[i], e = row_ptr[i + 1];
    float acc = 0.f;
    int t = s;
    for (; t + 7 < e; t += 8)
        acc += p[col[t]] + p[col[t + 1]] + p[col[t + 2]] + p[col[t + 3]]
             + p[col[t + 4]] + p[col[t + 5]] + p[col[t + 6]] + p[col[t + 7]];
    for (; t < e; t++) acc += p[col[t]];
    float di = 1.0f / fmaxf((float)(e - s), 1.0f);
    out[i] = acc * di + q[i];
}

// ---------------- launch ----------------

extern "C" void kernel_launch(void* const* d_in, const int* in_sizes, int n_in,
                              void* d_out, int out_size, void* d_ws, size_t ws_size,
                              hipStream_t stream) {
    const float* x    = (const float*)d_in[0];
    const int*   ei   = (const int*)d_in[1];
    const float* Wl1  = (const float*)d_in[2];
    const float* Wr1  = (const float*)d_in[3];
    const float* b1   = (const float*)d_in[4];
    const float* ln_g = (const float*)d_in[5];
    const float* ln_b = (const float*)d_in[6];
    const float* Wres = (const float*)d_in[7];
    const float* bres = (const float*)d_in[8];
    const float* Wl2  = (const float*)d_in[9];
    const float* Wr2  = (const float*)d_in[10];
    const float* b2   = (const float*)d_in[11];
    const float* Wl3  = (const float*)d_in[12];
    const float* Wr3  = (const float*)d_in[13];
    const float* b3   = (const float*)d_in[14];
    const float* Wl4  = (const float*)d_in[15];
    const float* Wr4  = (const float*)d_in[16];
    const float* b4   = (const float*)d_in[17];
    float* out = (float*)d_out;

    char* w = (char*)d_ws;
    size_t off = 0;
    auto alloc = [&](size_t bytes) -> void* {
        off = (off + 255) & ~(size_t)255;
        void* pp = w + off;
        off += bytes;
        return pp;
    };

    int* dbh      = (int*)alloc(64 * SORT_BLOCKS * 4);  // zeroed by memset
    int* bh2      = (int*)alloc(BH2_N * 4);
    int* bsum     = (int*)alloc(1024);
    int* deg      = (int*)alloc(N_NODES * 4);
    int* row_ptr  = (int*)alloc((N_NODES + 1) * 4);
    int* col      = (int*)alloc(N_EDGES * 4);
    int* ord      = (int*)alloc(N_NODES * 4);       // sorted slot -> original node (desc degree)
    unsigned short* Bt1  = (unsigned short*)alloc(256 * 128 * 2);
    unsigned short* Bt2  = (unsigned short*)alloc(128 * 256 * 2);
    unsigned short* Bt3  = (unsigned short*)alloc(128 * 256 * 2);
    unsigned short* xsrc = (unsigned short*)alloc((size_t)N_NODES * 64 * 2);   // x bf16 (compact)
    unsigned short* aggx = (unsigned short*)alloc((size_t)N_NODES * 64 * 2);   // agg(x)
    unsigned short* hsrc = (unsigned short*)alloc((size_t)N_NODES * 128 * 2);  // h bf16 (compact)
    unsigned short* aggh = (unsigned short*)alloc((size_t)N_NODES * 128 * 2);  // agg(h)
    int*   packed  = (int*)alloc((size_t)N_EDGES * 4);   // CSR build scratch
    float* p       = (float*)alloc(N_NODES * 4);
    float* q       = (float*)alloc(N_NODES * 4);
    (void)ws_size; (void)n_in; (void)in_sizes; (void)out_size;

    const int NB = (N_NODES + 255) / 256;

    // --- zero dsort hist, then mega front-end: wprep | edge hist -> bh2 | x->bf16 ---
    hipMemsetAsync(dbh, 0, 64 * SORT_BLOCKS * 4, stream);
    mega0_kernel<<<WPREP_BLOCKS + SCAT_BLOCKS + XBF_BLOCKS, 256, 0, stream>>>(
        Wr1, Wl1, Wres, Wl2, Wr2, Wl3, Wr3, Bt1, Bt2, Bt3, ei, bh2, x, xsrc);

    // --- CSR build (LDS-privatized scatter; bh2 matrix scan gives per-(bucket,block) bases) ---
    gscan_a_kernel<<<BHB, 256, 0, stream>>>(bh2, bsum, BH2_N);
    gscan_c_kernel<<<BHB, 256, 0, stream>>>(bh2, bsum, BHB, BH2_N);
    bkt_scatter2_kernel<<<SCAT_BLOCKS, 256, 0, stream>>>(ei, bh2, packed);
    bkt_build_kernel<<<NBKT, 256, 0, stream>>>(packed, bh2, deg, row_ptr, col, dbh);
    dsort_scat_kernel<<<SORT_BLOCKS, 256, 0, stream>>>(deg, dbh, ord);

    // --- layer 1: agg(x) -> aggx; fused GEMM+LN -> hsrc ---
    agg64_kernel<<<(N_NODES + 15) / 16, 256, 0, stream>>>(xsrc, aggx, row_ptr, col, ord);
    mgemm1_ln_kernel<<<GEMM_BLOCKS, 512, 0, stream>>>(xsrc, aggx, Bt1, b1, ln_g, ln_b, bres, hsrc);

    // --- layer 2: agg(h) -> aggh; GEMM [h|aggh] -> hsrc (bias+relu, in-place) ---
    agg128_kernel<<<(N_NODES + 7) / 8, 256, 0, stream>>>(hsrc, aggh, row_ptr, col, ord);
    mgemm_kernel<<<GEMM_BLOCKS, 512, 0, stream>>>(hsrc, aggh, Bt2, b2, hsrc);

    // --- layer 3: agg(h) -> aggh; fused GEMM+pq -> p, q (h3 never stored) ---
    agg128_kernel<<<(N_NODES + 7) / 8, 256, 0, stream>>>(hsrc, aggh, row_ptr, col, ord);
    mgemm_pq_kernel<<<GEMM_BLOCKS, 512, 0, stream>>>(hsrc, aggh, Bt3, b3, Wl4, Wr4, b4, p, q);

    // --- final ---
    final_kernel<<<NB, 256, 0, stream>>>(p, q, row_ptr, col, out);
}